// Round 1
// baseline (548.903 us; speedup 1.0000x reference)
//
#include <hip/hip_runtime.h>
#include <math.h>

namespace {
constexpr int B = 32, Q = 48, A = 48, D = 300;
constexpr int C = 512, K = 5, H = 512, P = 512, NCLS = 2;
constexpr int LOUT = A + K - 1;   // 52 conv output length
constexpr int CK = C * K;         // 2560
constexpr float EPS_COS = 1e-6f, EPS_BN = 1e-5f;
}

// Out[m, n] = sum_d X[m,d] * W[n,d]   (NT GEMM, both row-major with contiguous d)
// M multiple of 64, N multiple of 64; Kd arbitrary (guarded).
__global__ void gemm_nt(const float* __restrict__ X, const float* __restrict__ W,
                        float* __restrict__ Out, int M, int N, int Kd) {
  __shared__ float Xs[64][17];
  __shared__ float Ws[64][17];
  const int tid = threadIdx.x;
  const int tx = tid & 15, ty = tid >> 4;
  const int row0 = blockIdx.y * 64, col0 = blockIdx.x * 64;
  float acc[4][4] = {};
  for (int k0 = 0; k0 < Kd; k0 += 16) {
    const int gk = k0 + tx;
    const bool kv = gk < Kd;
#pragma unroll
    for (int i = 0; i < 4; ++i) {
      int r = ty + i * 16;
      Xs[r][tx] = kv ? X[(size_t)(row0 + r) * Kd + gk] : 0.f;
      Ws[r][tx] = kv ? W[(size_t)(col0 + r) * Kd + gk] : 0.f;
    }
    __syncthreads();
#pragma unroll
    for (int kk = 0; kk < 16; ++kk) {
      float xr[4], wr[4];
#pragma unroll
      for (int i = 0; i < 4; ++i) xr[i] = Xs[ty * 4 + i][kk];
#pragma unroll
      for (int j = 0; j < 4; ++j) wr[j] = Ws[tx * 4 + j][kk];
#pragma unroll
      for (int i = 0; i < 4; ++i)
#pragma unroll
        for (int j = 0; j < 4; ++j) acc[i][j] += xr[i] * wr[j];
    }
    __syncthreads();
  }
#pragma unroll
  for (int i = 0; i < 4; ++i)
#pragma unroll
    for (int j = 0; j < 4; ++j)
      Out[(size_t)(row0 + ty * 4 + i) * N + col0 + tx * 4 + j] = acc[i][j];
}

// row norms of q (B*Q rows) and a (B*A rows)
__global__ void norms_k(const float* __restrict__ q, const float* __restrict__ a,
                        float* __restrict__ qn, float* __restrict__ an) {
  int row = blockIdx.x;  // 0 .. B*Q + B*A - 1
  const float* src;
  float* dst;
  int r;
  if (row < B * Q) { src = q; dst = qn; r = row; }
  else             { src = a; dst = an; r = row - B * Q; }
  const float* x = src + (size_t)r * D;
  float s = 0.f;
  for (int d = threadIdx.x; d < D; d += 64) { float v = x[d]; s += v * v; }
  for (int off = 32; off; off >>= 1) s += __shfl_down(s, off);
  if (threadIdx.x == 0) dst[r] = sqrtf(s);
}

// cos[b,qi,ai] = dot(q[b,qi], a[b,ai]) / max(qn*an, eps)
__global__ void cos_k(const float* __restrict__ q, const float* __restrict__ a,
                      const float* __restrict__ qn, const float* __restrict__ an,
                      float* __restrict__ cosm) {
  __shared__ float qrow[D];
  int b = blockIdx.x / Q, qi = blockIdx.x % Q;
  const float* qp = q + ((size_t)b * Q + qi) * D;
  for (int d = threadIdx.x; d < D; d += 64) qrow[d] = qp[d];
  __syncthreads();
  int ai = threadIdx.x;
  if (ai < A) {
    const float* ap = a + ((size_t)b * A + ai) * D;
    float dot = 0.f;
    for (int d = 0; d < D; ++d) dot += qrow[d] * ap[d];
    float den = fmaxf(qn[b * Q + qi] * an[b * A + ai], EPS_COS);
    cosm[((size_t)b * Q + qi) * A + ai] = dot / den;
  }
}

// pooled[n,c] = relu(bias[c] + max_l sum_k S[n, l+k-4, c, k]); n<B from Sq, else Sa
__global__ void smpool_k(const float* __restrict__ Sq, const float* __restrict__ Sa,
                         const float* __restrict__ bias, float* __restrict__ pooled) {
  int n = blockIdx.x;                      // 0..2B-1
  int c = blockIdx.y * 256 + threadIdx.x;  // 0..C-1
  const float* S = (n < B) ? Sq : Sa;
  int nn = (n < B) ? n : n - B;
  float best = -1e30f;
  for (int l = 0; l < LOUT; ++l) {
    float z = 0.f;
#pragma unroll
    for (int k = 0; k < K; ++k) {
      int pos = l + k - (K - 1);
      if (pos >= 0 && pos < A)
        z += S[((size_t)nn * A + pos) * CK + c * K + k];
    }
    best = fmaxf(best, z);
  }
  pooled[(size_t)n * C + c] = fmaxf(best + bias[c], 0.f);
}

// out[n,h] = bias[h] + sum_c in[n,c] * W[h,c]
__global__ void fc_k(const float* __restrict__ in, const float* __restrict__ W,
                     const float* __restrict__ bias, float* __restrict__ out) {
  __shared__ float row[C];
  int n = blockIdx.x;
  int h = blockIdx.y * 256 + threadIdx.x;
  for (int c = threadIdx.x; c < C; c += 256) row[c] = in[(size_t)n * C + c];
  __syncthreads();
  float acc = bias[h];
  const float* w = W + (size_t)h * C;
  for (int c = 0; c < C; ++c) acc += row[c] * w[c];
  out[(size_t)n * H + h] = acc;
}

// pooled_ctx[bq,c] = relu(bias[c] + max_l sum_k cos[bq, l+k-4] * Sa[b, l+k-4, c, k])
__global__ void ctxpool_k(const float* __restrict__ Sa, const float* __restrict__ cosm,
                          const float* __restrict__ bias, float* __restrict__ pooled) {
  __shared__ float cr[A];
  int bq = blockIdx.x;
  int b = bq / Q;
  int c = blockIdx.y * 256 + threadIdx.x;
  if (threadIdx.x < A) cr[threadIdx.x] = cosm[(size_t)bq * A + threadIdx.x];
  __syncthreads();
  float best = -1e30f;
  for (int l = 0; l < LOUT; ++l) {
    float z = 0.f;
#pragma unroll
    for (int k = 0; k < K; ++k) {
      int pos = l + k - (K - 1);
      if (pos >= 0 && pos < A)
        z += cr[pos] * Sa[((size_t)b * A + pos) * CK + c * K + k];
    }
    best = fmaxf(best, z);
  }
  pooled[(size_t)bq * C + c] = fmaxf(best + bias[c], 0.f);
}

// pbar[b,c] = mean over qi of pooled[b*Q+qi, c]
__global__ void meanq_k(const float* __restrict__ pooled, float* __restrict__ pbar) {
  int b = blockIdx.x;
  int c = blockIdx.y * 256 + threadIdx.x;
  float s = 0.f;
  for (int qi = 0; qi < Q; ++qi) s += pooled[((size_t)b * Q + qi) * C + c];
  pbar[(size_t)b * C + c] = s * (1.0f / Q);
}

// comb[b,p] = proj_b[p] + [acnn|bcnn|attn][b,:] . proj_w[p,:]
__global__ void proj_k(const float* __restrict__ acnn, const float* __restrict__ bcnn,
                       const float* __restrict__ attn, const float* __restrict__ W,
                       const float* __restrict__ bias, float* __restrict__ comb) {
  __shared__ float cat[3 * H];
  int b = blockIdx.x;
  int p = threadIdx.x;  // block = 512
  cat[p] = acnn[(size_t)b * H + p];
  cat[H + p] = bcnn[(size_t)b * H + p];
  cat[2 * H + p] = attn[(size_t)b * H + p];
  __syncthreads();
  const float* w = W + (size_t)p * (3 * H);
  float acc = bias[p];
  for (int j = 0; j < 3 * H; ++j) acc += cat[j] * w[j];
  comb[(size_t)b * P + p] = acc;
}

// batchnorm (training stats over B) + tanh
__global__ void bn_k(const float* __restrict__ comb, const float* __restrict__ gamma,
                     const float* __restrict__ beta, float* __restrict__ tout) {
  int p = threadIdx.x;  // block = 512, grid = 1
  float s = 0.f;
  for (int r = 0; r < B; ++r) s += comb[(size_t)r * P + p];
  float mu = s / B;
  float v = 0.f;
  for (int r = 0; r < B; ++r) { float d = comb[(size_t)r * P + p] - mu; v += d * d; }
  float inv = rsqrtf(v / B + EPS_BN);
  float g = gamma[p], be = beta[p];
  for (int r = 0; r < B; ++r)
    tout[(size_t)r * P + p] = tanhf((comb[(size_t)r * P + p] - mu) * inv * g + be);
}

// logits[b,cl] = out_b[cl] + tcomb[b,:] . out_w[cl,:]
__global__ void out_k(const float* __restrict__ t, const float* __restrict__ W,
                      const float* __restrict__ bias, float* __restrict__ out) {
  int tid = threadIdx.x;  // 64 threads
  int b = tid >> 1, cl = tid & 1;
  float acc = bias[cl];
  const float* w = W + (size_t)cl * P;
  const float* x = t + (size_t)b * P;
  for (int p = 0; p < P; ++p) acc += x[p] * w[p];
  out[b * NCLS + cl] = acc;
}

extern "C" void kernel_launch(void* const* d_in, const int* in_sizes, int n_in,
                              void* d_out, int out_size, void* d_ws, size_t ws_size,
                              hipStream_t stream) {
  const float* q       = (const float*)d_in[0];
  const float* a       = (const float*)d_in[1];
  const float* sm_w    = (const float*)d_in[2];
  const float* sm_b    = (const float*)d_in[3];
  const float* sm_fcw  = (const float*)d_in[4];
  const float* sm_fcb  = (const float*)d_in[5];
  const float* ctx_w   = (const float*)d_in[6];
  const float* ctx_b   = (const float*)d_in[7];
  const float* ctx_fcw = (const float*)d_in[8];
  const float* ctx_fcb = (const float*)d_in[9];
  const float* proj_w  = (const float*)d_in[10];
  const float* proj_b  = (const float*)d_in[11];
  const float* gamma   = (const float*)d_in[12];
  const float* beta    = (const float*)d_in[13];
  const float* out_w   = (const float*)d_in[14];
  const float* out_b   = (const float*)d_in[15];

  float* ws = (float*)d_ws;
  size_t off = 0;
  auto alloc = [&](size_t n) { float* p = ws + off; off += n; return p; };
  float* Sq     = alloc((size_t)B * Q * CK);   // q . sm_w
  float* Sa_sm  = alloc((size_t)B * A * CK);   // a . sm_w
  float* Sa_ctx = alloc((size_t)B * A * CK);   // a . ctx_w
  float* cosm   = alloc((size_t)B * Q * A);
  float* qn     = alloc((size_t)B * Q);
  float* an     = alloc((size_t)B * A);
  float* pooled = alloc((size_t)2 * B * C);    // [q-pooled | a-pooled]
  float* acnn   = alloc((size_t)B * H);
  float* bcnn   = alloc((size_t)B * H);
  float* pctx   = alloc((size_t)B * Q * C);
  float* pbar   = alloc((size_t)B * C);
  float* attnf  = alloc((size_t)B * H);
  float* comb   = alloc((size_t)B * P);
  float* tcomb  = alloc((size_t)B * P);

  dim3 gg(CK / 64, (B * Q) / 64);  // 40 x 24
  gemm_nt<<<gg, 256, 0, stream>>>(q, sm_w, Sq, B * Q, CK, D);
  gemm_nt<<<gg, 256, 0, stream>>>(a, sm_w, Sa_sm, B * A, CK, D);
  gemm_nt<<<gg, 256, 0, stream>>>(a, ctx_w, Sa_ctx, B * A, CK, D);

  norms_k<<<B * (Q + A), 64, 0, stream>>>(q, a, qn, an);
  cos_k<<<B * Q, 64, 0, stream>>>(q, a, qn, an, cosm);

  smpool_k<<<dim3(2 * B, C / 256), 256, 0, stream>>>(Sq, Sa_sm, sm_b, pooled);
  fc_k<<<dim3(B, H / 256), 256, 0, stream>>>(pooled, sm_fcw, sm_fcb, acnn);
  fc_k<<<dim3(B, H / 256), 256, 0, stream>>>(pooled + (size_t)B * C, sm_fcw, sm_fcb, bcnn);

  ctxpool_k<<<dim3(B * Q, C / 256), 256, 0, stream>>>(Sa_ctx, cosm, ctx_b, pctx);
  meanq_k<<<dim3(B, C / 256), 256, 0, stream>>>(pctx, pbar);
  fc_k<<<dim3(B, H / 256), 256, 0, stream>>>(pbar, ctx_fcw, ctx_fcb, attnf);

  proj_k<<<B, P, 0, stream>>>(acnn, bcnn, attnf, proj_w, proj_b, comb);
  bn_k<<<1, P, 0, stream>>>(comb, gamma, beta, tcomb);
  out_k<<<1, 64, 0, stream>>>(tcomb, out_w, out_b, (float*)d_out);
}

// Round 2
// 237.053 us; speedup vs baseline: 2.3155x; 2.3155x over previous
//
#include <hip/hip_runtime.h>
#include <math.h>

namespace {
constexpr int B = 32, Q = 48, A = 48, D = 300;
constexpr int C = 512, K = 5, H = 512, P = 512, NCLS = 2;
constexpr int CK = C * K;         // 2560
constexpr int M = B * Q;          // 1536 rows for every GEMM
constexpr int CT = 32;            // c-tile for pooling kernels
constexpr int LP = 60;            // padded position axis (pos+4, up to l+4=58)
constexpr float EPS_COS = 1e-6f, EPS_BN = 1e-5f;
}

// ---------------------------------------------------------------------------
// Batched NT GEMM: Out[m,n] = sum_d X[m,d] * W[n,d];  z selects (X,W,Out).
// M=1536, N=2560, Kd=300. 64x64 tile, 256 threads, 4x4 acc, transposed LDS
// so fragments are ds_read_b128.
// ---------------------------------------------------------------------------
__global__ void gemm_nt3(const float* __restrict__ q, const float* __restrict__ a,
                         const float* __restrict__ sm_w, const float* __restrict__ ctx_w,
                         float* __restrict__ Sq, float* __restrict__ Sa_sm,
                         float* __restrict__ Sa_ctx) {
  const int z = blockIdx.z;
  const float* X = (z == 0) ? q : a;
  const float* W = (z == 2) ? ctx_w : sm_w;
  float* Out = (z == 0) ? Sq : (z == 1) ? Sa_sm : Sa_ctx;

  __shared__ float Xs[16][68];  // [k][row], pad 68 -> write banks (tx*4+r)%32, 2-way max
  __shared__ float Ws[16][68];
  const int tid = threadIdx.x;
  const int tx = tid & 15, ty = tid >> 4;
  const int row0 = blockIdx.y * 64, col0 = blockIdx.x * 64;
  float acc[4][4] = {};

  for (int k0 = 0; k0 < D; k0 += 16) {
    const int gk = k0 + tx;
    const bool kv = gk < D;
#pragma unroll
    for (int i = 0; i < 4; ++i) {
      int r = ty + i * 16;
      Xs[tx][r] = kv ? X[(size_t)(row0 + r) * D + gk] : 0.f;
      Ws[tx][r] = kv ? W[(size_t)(col0 + r) * D + gk] : 0.f;
    }
    __syncthreads();
#pragma unroll
    for (int kk = 0; kk < 16; ++kk) {
      const float4 xv = *(const float4*)&Xs[kk][ty * 4];
      const float4 wv = *(const float4*)&Ws[kk][tx * 4];
      const float xr[4] = {xv.x, xv.y, xv.z, xv.w};
      const float wr[4] = {wv.x, wv.y, wv.z, wv.w};
#pragma unroll
      for (int i = 0; i < 4; ++i)
#pragma unroll
        for (int j = 0; j < 4; ++j) acc[i][j] += xr[i] * wr[j];
    }
    __syncthreads();
  }
#pragma unroll
  for (int i = 0; i < 4; ++i) {
    float4 o = {acc[i][0], acc[i][1], acc[i][2], acc[i][3]};
    *(float4*)&Out[(size_t)(row0 + ty * 4 + i) * CK + col0 + tx * 4] = o;
  }
}

// ---------------------------------------------------------------------------
// cosine similarity, norms fused.  block = (b,qi), 64 threads.
// ---------------------------------------------------------------------------
__global__ void cos_k(const float* __restrict__ q, const float* __restrict__ a,
                      float* __restrict__ cosm) {
  __shared__ float qrow[D];
  __shared__ float qn_sh;
  const int bq = blockIdx.x;
  const int b = bq / Q;
  const int tid = threadIdx.x;
  const float* qp = q + (size_t)bq * D;
  float qsq = 0.f;
  for (int d = tid; d < D; d += 64) { float v = qp[d]; qrow[d] = v; qsq += v * v; }
#pragma unroll
  for (int off = 32; off; off >>= 1) qsq += __shfl_down(qsq, off);
  if (tid == 0) qn_sh = sqrtf(qsq);
  __syncthreads();
  if (tid < A) {
    const float* ap = a + ((size_t)b * A + tid) * D;
    float dot = 0.f, asq = 0.f;
    for (int d = 0; d < D; ++d) { float av = ap[d]; dot += qrow[d] * av; asq += av * av; }
    float den = fmaxf(qn_sh * sqrtf(asq), EPS_COS);
    cosm[(size_t)bq * A + tid] = dot / den;
  }
}

// ---------------------------------------------------------------------------
// smpool: pooled[n,c] = relu(bias[c] + max_l sum_k S[n, l+k-4, c, k])
// block = (ct, n); stage padded Sa slice in LDS.
// ---------------------------------------------------------------------------
__global__ void smpool_k(const float* __restrict__ Sq, const float* __restrict__ Sa,
                         const float* __restrict__ bias, float* __restrict__ pooled) {
  __shared__ float sa[LP * CT * K];  // 38.4 KB
  __shared__ float red[8 * CT];
  const int n = blockIdx.y;          // 0..2B-1
  const int ct = blockIdx.x;         // 0..15
  const int tid = threadIdx.x;       // 256
  const float* S = (n < B) ? Sq : Sa;
  const int nn = (n < B) ? n : n - B;

  for (int i = tid; i < LP * CT * K; i += 256) sa[i] = 0.f;
  __syncthreads();
  for (int i = tid; i < A * CT * K; i += 256) {
    int pos = i / (CT * K), j = i % (CT * K);
    sa[(pos + 4) * (CT * K) + j] = S[((size_t)nn * A + pos) * CK + ct * CT * K + j];
  }
  __syncthreads();

  const int clane = tid & 31, part = tid >> 5;  // 8 parts x 7 l's
  float best = -1e30f;
#pragma unroll
  for (int i = 0; i < 7; ++i) {
    int l = part * 7 + i;
    float zv = 0.f;
#pragma unroll
    for (int k = 0; k < K; ++k) zv += sa[(l + k) * (CT * K) + clane * K + k];
    if (l < A + K - 1) best = fmaxf(best, zv);
  }
  red[part * CT + clane] = best;
  __syncthreads();
  if (tid < CT) {
    float m = red[tid];
#pragma unroll
    for (int g = 1; g < 8; ++g) m = fmaxf(m, red[g * CT + tid]);
    pooled[(size_t)n * C + ct * CT + tid] = fmaxf(m + bias[ct * CT + tid], 0.f);
  }
}

// ---------------------------------------------------------------------------
// ctxpool fused with mean over q':
// pbar[b,c] = (1/Q) sum_q' relu(bias[c] + max_l sum_k cos[b,q',l+k-4]*Sa[b,l+k-4,c,k])
// block = (ct, b), 256 threads = 8 q'-groups x 32 c-lanes; 6 q' per thread,
// circular 5-slot cos window in registers (unroll-by-5, static indices).
// ---------------------------------------------------------------------------
__global__ void ctxpool_k(const float* __restrict__ Sa, const float* __restrict__ cosm,
                          const float* __restrict__ bias, float* __restrict__ pbar) {
  __shared__ float sa[LP * CT * K];   // 38.4 KB
  __shared__ float cp[Q * LP];        // 11.5 KB
  __shared__ float red[8 * CT];
  const int b = blockIdx.y;
  const int ct = blockIdx.x;
  const int tid = threadIdx.x;

  for (int i = tid; i < LP * CT * K; i += 256) sa[i] = 0.f;
  for (int i = tid; i < Q * LP; i += 256) cp[i] = 0.f;
  __syncthreads();
  for (int i = tid; i < A * CT * K; i += 256) {
    int pos = i / (CT * K), j = i % (CT * K);
    sa[(pos + 4) * (CT * K) + j] = Sa[((size_t)b * A + pos) * CK + ct * CT * K + j];
  }
  for (int i = tid; i < Q * A; i += 256) {
    int qi = i / A, pos = i % A;
    cp[qi * LP + pos + 4] = cosm[((size_t)b * Q + qi) * A + pos];
  }
  __syncthreads();

  const int clane = tid & 31, grp = tid >> 5;  // q' = grp*6 + j
  float cw[6][5];
#pragma unroll
  for (int j = 0; j < 6; ++j) {
#pragma unroll
    for (int s = 0; s < 4; ++s) cw[j][s] = cp[(grp * 6 + j) * LP + s];
    cw[j][4] = 0.f;
  }
  float best[6];
#pragma unroll
  for (int j = 0; j < 6; ++j) best[j] = -1e30f;

  for (int l5 = 0; l5 <= 50; l5 += 5) {
#pragma unroll
    for (int p = 0; p < 5; ++p) {
      const int l = l5 + p;  // 0..54
      const int snew = (p + 4) % 5;
#pragma unroll
      for (int j = 0; j < 6; ++j) cw[j][snew] = cp[(grp * 6 + j) * LP + l + 4];
      float sk[5];
#pragma unroll
      for (int k = 0; k < K; ++k) sk[k] = sa[(l + k) * (CT * K) + clane * K + k];
      const bool live = (l < A + K - 1);
#pragma unroll
      for (int j = 0; j < 6; ++j) {
        float zv = 0.f;
#pragma unroll
        for (int k = 0; k < K; ++k) zv += cw[j][(p + k) % 5] * sk[k];
        if (live) best[j] = fmaxf(best[j], zv);
      }
    }
  }
  const float bc = bias[ct * CT + clane];
  float s = 0.f;
#pragma unroll
  for (int j = 0; j < 6; ++j) s += fmaxf(best[j] + bc, 0.f);
  red[grp * CT + clane] = s;
  __syncthreads();
  if (tid < CT) {
    float tot = 0.f;
#pragma unroll
    for (int g = 0; g < 8; ++g) tot += red[g * CT + tid];
    pbar[(size_t)b * C + ct * CT + tid] = tot * (1.0f / Q);
  }
}

// ---------------------------------------------------------------------------
// batched FC: out[n,h] = bias[h] + in[n,:] . W[h,:]   (z selects triple)
// ---------------------------------------------------------------------------
__global__ void fc_k(const float* __restrict__ pooled, const float* __restrict__ pbar,
                     const float* __restrict__ smW, const float* __restrict__ smb,
                     const float* __restrict__ ctxW, const float* __restrict__ ctxb,
                     float* __restrict__ acnn, float* __restrict__ bcnn,
                     float* __restrict__ attnf) {
  __shared__ float row[C];
  const int z = blockIdx.z;
  const float* in = (z == 0) ? pooled : (z == 1) ? pooled + (size_t)B * C : pbar;
  const float* Wm = (z == 2) ? ctxW : smW;
  const float* bs = (z == 2) ? ctxb : smb;
  float* out = (z == 0) ? acnn : (z == 1) ? bcnn : attnf;
  const int n = blockIdx.x;
  const int h = blockIdx.y * 256 + threadIdx.x;
  for (int c = threadIdx.x; c < C; c += 256) row[c] = in[(size_t)n * C + c];
  __syncthreads();
  float acc = bs[h];
  const float* w = Wm + (size_t)h * C;
  for (int c = 0; c < C; ++c) acc += row[c] * w[c];
  out[(size_t)n * H + h] = acc;
}

// transpose proj_w [P][3H] -> projT [3H][P]
__global__ void tpose_k(const float* __restrict__ in, float* __restrict__ outT) {
  __shared__ float tile[32][33];
  const int j0 = blockIdx.x * 32, p0 = blockIdx.y * 32;
  const int tx = threadIdx.x, ty = threadIdx.y;
  for (int i = ty; i < 32; i += 8) tile[i][tx] = in[(size_t)(p0 + i) * (3 * H) + j0 + tx];
  __syncthreads();
  for (int i = ty; i < 32; i += 8) outT[(size_t)(j0 + i) * P + p0 + tx] = tile[tx][i];
}

// comb[b,p] = proj_b[p] + cat[b,:] . projT[:,p]   (coalesced)
__global__ void proj_k(const float* __restrict__ acnn, const float* __restrict__ bcnn,
                       const float* __restrict__ attn, const float* __restrict__ WT,
                       const float* __restrict__ bias, float* __restrict__ comb) {
  __shared__ float cat[3 * H];
  const int b = blockIdx.x;
  const int p = threadIdx.x;  // 512
  cat[p] = acnn[(size_t)b * H + p];
  cat[H + p] = bcnn[(size_t)b * H + p];
  cat[2 * H + p] = attn[(size_t)b * H + p];
  __syncthreads();
  float acc = bias[p];
  for (int j = 0; j < 3 * H; ++j) acc += cat[j] * WT[(size_t)j * P + p];
  comb[(size_t)b * P + p] = acc;
}

// batchnorm(train) + tanh + final FC, one block of 512 threads
__global__ void bnout_k(const float* __restrict__ comb, const float* __restrict__ gamma,
                        const float* __restrict__ beta, const float* __restrict__ out_w,
                        const float* __restrict__ out_b, float* __restrict__ out) {
  __shared__ float t[B][P];  // 64 KB
  const int p = threadIdx.x;
  float v[B];
  float mu = 0.f;
#pragma unroll
  for (int r = 0; r < B; ++r) { v[r] = comb[(size_t)r * P + p]; mu += v[r]; }
  mu *= (1.0f / B);
  float var = 0.f;
#pragma unroll
  for (int r = 0; r < B; ++r) { float d = v[r] - mu; var += d * d; }
  const float inv = rsqrtf(var * (1.0f / B) + EPS_BN);
  const float g = gamma[p], be = beta[p];
#pragma unroll
  for (int r = 0; r < B; ++r) t[r][p] = tanhf((v[r] - mu) * inv * g + be);
  __syncthreads();
  const int o = p >> 3, lane8 = p & 7;  // 64 outputs x 8 lanes
  const int bb = o >> 1, cl = o & 1;
  float acc = 0.f;
  for (int j = lane8; j < P; j += 8) acc += t[bb][j] * out_w[cl * P + j];
#pragma unroll
  for (int off = 4; off; off >>= 1) acc += __shfl_down(acc, off);
  if (lane8 == 0) out[bb * NCLS + cl] = acc + out_b[cl];
}

extern "C" void kernel_launch(void* const* d_in, const int* in_sizes, int n_in,
                              void* d_out, int out_size, void* d_ws, size_t ws_size,
                              hipStream_t stream) {
  const float* q       = (const float*)d_in[0];
  const float* a       = (const float*)d_in[1];
  const float* sm_w    = (const float*)d_in[2];
  const float* sm_b    = (const float*)d_in[3];
  const float* sm_fcw  = (const float*)d_in[4];
  const float* sm_fcb  = (const float*)d_in[5];
  const float* ctx_w   = (const float*)d_in[6];
  const float* ctx_b   = (const float*)d_in[7];
  const float* ctx_fcw = (const float*)d_in[8];
  const float* ctx_fcb = (const float*)d_in[9];
  const float* proj_w  = (const float*)d_in[10];
  const float* proj_b  = (const float*)d_in[11];
  const float* gamma   = (const float*)d_in[12];
  const float* beta    = (const float*)d_in[13];
  const float* out_w   = (const float*)d_in[14];
  const float* out_b   = (const float*)d_in[15];

  float* ws = (float*)d_ws;
  size_t off = 0;
  auto alloc = [&](size_t n) { float* p = ws + off; off += n; return p; };
  float* Sq     = alloc((size_t)M * CK);
  float* Sa_sm  = alloc((size_t)M * CK);
  float* Sa_ctx = alloc((size_t)M * CK);
  float* cosm   = alloc((size_t)B * Q * A);
  float* pooled = alloc((size_t)2 * B * C);
  float* pbar   = alloc((size_t)B * C);
  float* acnn   = alloc((size_t)B * H);
  float* bcnn   = alloc((size_t)B * H);
  float* attnf  = alloc((size_t)B * H);
  float* projT  = alloc((size_t)3 * H * P);
  float* comb   = alloc((size_t)B * P);

  gemm_nt3<<<dim3(CK / 64, M / 64, 3), 256, 0, stream>>>(q, a, sm_w, ctx_w, Sq, Sa_sm, Sa_ctx);
  cos_k<<<B * Q, 64, 0, stream>>>(q, a, cosm);
  tpose_k<<<dim3(3 * H / 32, P / 32), dim3(32, 8), 0, stream>>>(proj_w, projT);

  smpool_k<<<dim3(C / CT, 2 * B), 256, 0, stream>>>(Sq, Sa_sm, sm_b, pooled);
  ctxpool_k<<<dim3(C / CT, B), 256, 0, stream>>>(Sa_ctx, cosm, ctx_b, pbar);

  fc_k<<<dim3(B, H / 256, 3), 256, 0, stream>>>(pooled, pbar, sm_fcw, sm_fcb,
                                                ctx_fcw, ctx_fcb, acnn, bcnn, attnf);
  proj_k<<<B, P, 0, stream>>>(acnn, bcnn, attnf, projT, proj_b, comb);
  bnout_k<<<1, P, 0, stream>>>(comb, gamma, beta, out_w, out_b, (float*)d_out);
}

// Round 3
// 168.978 us; speedup vs baseline: 3.2484x; 1.4029x over previous
//
#include <hip/hip_runtime.h>
#include <math.h>
#include <stdint.h>

namespace {
constexpr int B = 32, Q = 48, A = 48, D = 300;
constexpr int C = 512, K = 5, H = 512, P = 512, NCLS = 2;
constexpr int CK = C * K;         // 2560
constexpr int M = B * Q;          // 1536 rows for every GEMM
constexpr int KP = 320;           // K padded to 10*32 for bf16 MFMA
constexpr int CT = 32;            // c-tile for pooling kernels
constexpr int LP = 60;            // padded position axis
constexpr float EPS_COS = 1e-6f, EPS_BN = 1e-5f;
}
using short8 = __attribute__((ext_vector_type(8))) short;
using f32x4  = __attribute__((ext_vector_type(4))) float;

// ---------------------------------------------------------------------------
// fp32 -> bf16 (RNE) with zero-pad K: 300 -> 320. One 8-elem chunk per thread.
// rows: q(1536) | a(1536) | sm_w(2560) | ctx_w(2560) = 8192 rows x 40 chunks
// ---------------------------------------------------------------------------
__global__ void cvt_k(const float* __restrict__ q, const float* __restrict__ a,
                      const float* __restrict__ smw, const float* __restrict__ ctxw,
                      short* __restrict__ qb, short* __restrict__ ab,
                      short* __restrict__ smb, short* __restrict__ ctxb) {
  const int idx = blockIdx.x * 256 + threadIdx.x;
  const int row = idx / 40, ch = idx - row * 40;
  const float* src; short* dst; int r;
  if (row < M)            { src = q;    dst = qb;   r = row; }
  else if (row < 2 * M)   { src = a;    dst = ab;   r = row - M; }
  else if (row < 2*M+CK)  { src = smw;  dst = smb;  r = row - 2 * M; }
  else                    { src = ctxw; dst = ctxb; r = row - 2 * M - CK; }
  short tmp[8];
#pragma unroll
  for (int e = 0; e < 8; ++e) {
    const int k = ch * 8 + e;
    float v = (k < D) ? src[(size_t)r * D + k] : 0.f;
    uint32_t u = __builtin_bit_cast(uint32_t, v);
    uint32_t rb = (u + 0x7fffu + ((u >> 16) & 1u)) >> 16;  // RNE
    tmp[e] = (short)rb;
  }
  *(int4*)&dst[(size_t)r * KP + ch * 8] = *(const int4*)tmp;
}

// ---------------------------------------------------------------------------
// Batched NT GEMM via bf16 MFMA, fp32 out: Out[m,n] = sum_d X[m,d]*W[n,d].
// 128x128 tile, 4 waves (2x2), 16x16x32 MFMA 4x4 frags/wave, BK=64,
// XOR-swizzled LDS (write+read), prefetch next K-step under MFMA.
// ---------------------------------------------------------------------------
__global__ void __launch_bounds__(256)
gemm_mfma(const short* __restrict__ qb, const short* __restrict__ ab,
          const short* __restrict__ smb, const short* __restrict__ ctxb,
          float* __restrict__ Sq, float* __restrict__ Sa_sm, float* __restrict__ Sa_ctx) {
  const int z = blockIdx.z;
  const short* X = (z == 0) ? qb : ab;
  const short* W = (z == 2) ? ctxb : smb;
  float* Out = (z == 0) ? Sq : (z == 1) ? Sa_sm : Sa_ctx;

  __shared__ short As[128 * 64];  // 16 KB, [row][64k], slot s holds chunk s^(row&7)
  __shared__ short Bs[128 * 64];
  const int tid = threadIdx.x, lane = tid & 63, wv = tid >> 6;
  const int wr = wv >> 1, wc = wv & 1;
  const int row0 = blockIdx.y * 128, col0 = blockIdx.x * 128;

  int rS[4], jS[4];
#pragma unroll
  for (int i = 0; i < 4; ++i) { int c = i * 256 + tid; rS[i] = c >> 3; jS[i] = c & 7; }

  int4 pA[4], pB[4];
  auto issue = [&](int ks) {
#pragma unroll
    for (int i = 0; i < 4; ++i) {
      pA[i] = *(const int4*)(X + (size_t)(row0 + rS[i]) * KP + ks * 64 + jS[i] * 8);
      pB[i] = *(const int4*)(W + (size_t)(col0 + rS[i]) * KP + ks * 64 + jS[i] * 8);
    }
  };

  f32x4 acc[4][4];
#pragma unroll
  for (int mi = 0; mi < 4; ++mi)
#pragma unroll
    for (int ni = 0; ni < 4; ++ni) acc[mi][ni] = f32x4{0.f, 0.f, 0.f, 0.f};

  issue(0);
  for (int ks = 0; ks < KP / 64; ++ks) {
    __syncthreads();  // prev-step readers done before overwrite
#pragma unroll
    for (int i = 0; i < 4; ++i) {
      const int soff = rS[i] * 64 + (jS[i] ^ (rS[i] & 7)) * 8;
      *(int4*)&As[soff] = pA[i];
      *(int4*)&Bs[soff] = pB[i];
    }
    if (ks < KP / 64 - 1) issue(ks + 1);  // overlap next loads with MFMA
    __syncthreads();
#pragma unroll
    for (int kk = 0; kk < 2; ++kk) {
      const int kbase = kk * 32 + (lane >> 4) * 8;   // shorts
      const int swz = (lane & 7) << 3;               // shorts
      short8 af[4], bf[4];
#pragma unroll
      for (int mi = 0; mi < 4; ++mi) {
        const int rowa = wr * 64 + mi * 16 + (lane & 15);
        const int rowb = wc * 64 + mi * 16 + (lane & 15);
        af[mi] = *(const short8*)&As[rowa * 64 + (kbase ^ swz)];
        bf[mi] = *(const short8*)&Bs[rowb * 64 + (kbase ^ swz)];
      }
#pragma unroll
      for (int mi = 0; mi < 4; ++mi)
#pragma unroll
        for (int ni = 0; ni < 4; ++ni)
          acc[mi][ni] = __builtin_amdgcn_mfma_f32_16x16x32_bf16(af[mi], bf[ni], acc[mi][ni], 0, 0, 0);
    }
  }
  const int orow = (lane >> 4) * 4, ocol = lane & 15;
#pragma unroll
  for (int mi = 0; mi < 4; ++mi)
#pragma unroll
    for (int ni = 0; ni < 4; ++ni) {
      const size_t base = (size_t)(row0 + wr * 64 + mi * 16 + orow) * CK
                        + col0 + wc * 64 + ni * 16 + ocol;
#pragma unroll
      for (int r = 0; r < 4; ++r) Out[base + (size_t)r * CK] = acc[mi][ni][r];
    }
}

// ---------------------------------------------------------------------------
// cosine similarity, norms fused.  block = (b,qi), 64 threads.
// ---------------------------------------------------------------------------
__global__ void cos_k(const float* __restrict__ q, const float* __restrict__ a,
                      float* __restrict__ cosm) {
  __shared__ float qrow[D];
  __shared__ float qn_sh;
  const int bq = blockIdx.x;
  const int b = bq / Q;
  const int tid = threadIdx.x;
  const float* qp = q + (size_t)bq * D;
  float qsq = 0.f;
  for (int d = tid; d < D; d += 64) { float v = qp[d]; qrow[d] = v; qsq += v * v; }
#pragma unroll
  for (int off = 32; off; off >>= 1) qsq += __shfl_down(qsq, off);
  if (tid == 0) qn_sh = sqrtf(qsq);
  __syncthreads();
  if (tid < A) {
    const float* ap = a + ((size_t)b * A + tid) * D;
    float dot = 0.f, asq = 0.f;
    for (int d = 0; d < D; ++d) { float av = ap[d]; dot += qrow[d] * av; asq += av * av; }
    float den = fmaxf(qn_sh * sqrtf(asq), EPS_COS);
    cosm[(size_t)bq * A + tid] = dot / den;
  }
}

// ---------------------------------------------------------------------------
// smpool: pooled[n,c] = relu(bias[c] + max_l sum_k S[n, l+k-4, c, k])
// ---------------------------------------------------------------------------
__global__ void smpool_k(const float* __restrict__ Sq, const float* __restrict__ Sa,
                         const float* __restrict__ bias, float* __restrict__ pooled) {
  __shared__ float sa[LP * CT * K];
  __shared__ float red[8 * CT];
  const int n = blockIdx.y;
  const int ct = blockIdx.x;
  const int tid = threadIdx.x;
  const float* S = (n < B) ? Sq : Sa;
  const int nn = (n < B) ? n : n - B;

  for (int i = tid; i < LP * CT * K; i += 256) sa[i] = 0.f;
  __syncthreads();
  for (int i = tid; i < A * CT * K; i += 256) {
    int pos = i / (CT * K), j = i % (CT * K);
    sa[(pos + 4) * (CT * K) + j] = S[((size_t)nn * A + pos) * CK + ct * CT * K + j];
  }
  __syncthreads();

  const int clane = tid & 31, part = tid >> 5;
  float best = -1e30f;
#pragma unroll
  for (int i = 0; i < 7; ++i) {
    int l = part * 7 + i;
    float zv = 0.f;
#pragma unroll
    for (int k = 0; k < K; ++k) zv += sa[(l + k) * (CT * K) + clane * K + k];
    if (l < A + K - 1) best = fmaxf(best, zv);
  }
  red[part * CT + clane] = best;
  __syncthreads();
  if (tid < CT) {
    float m = red[tid];
#pragma unroll
    for (int g = 1; g < 8; ++g) m = fmaxf(m, red[g * CT + tid]);
    pooled[(size_t)n * C + ct * CT + tid] = fmaxf(m + bias[ct * CT + tid], 0.f);
  }
}

// ---------------------------------------------------------------------------
// ctxpool fused with mean over q'.
// ---------------------------------------------------------------------------
__global__ void ctxpool_k(const float* __restrict__ Sa, const float* __restrict__ cosm,
                          const float* __restrict__ bias, float* __restrict__ pbar) {
  __shared__ float sa[LP * CT * K];
  __shared__ float cp[Q * LP];
  __shared__ float red[8 * CT];
  const int b = blockIdx.y;
  const int ct = blockIdx.x;
  const int tid = threadIdx.x;

  for (int i = tid; i < LP * CT * K; i += 256) sa[i] = 0.f;
  for (int i = tid; i < Q * LP; i += 256) cp[i] = 0.f;
  __syncthreads();
  for (int i = tid; i < A * CT * K; i += 256) {
    int pos = i / (CT * K), j = i % (CT * K);
    sa[(pos + 4) * (CT * K) + j] = Sa[((size_t)b * A + pos) * CK + ct * CT * K + j];
  }
  for (int i = tid; i < Q * A; i += 256) {
    int qi = i / A, pos = i % A;
    cp[qi * LP + pos + 4] = cosm[((size_t)b * Q + qi) * A + pos];
  }
  __syncthreads();

  const int clane = tid & 31, grp = tid >> 5;
  float cw[6][5];
#pragma unroll
  for (int j = 0; j < 6; ++j) {
#pragma unroll
    for (int s = 0; s < 4; ++s) cw[j][s] = cp[(grp * 6 + j) * LP + s];
    cw[j][4] = 0.f;
  }
  float best[6];
#pragma unroll
  for (int j = 0; j < 6; ++j) best[j] = -1e30f;

  for (int l5 = 0; l5 <= 50; l5 += 5) {
#pragma unroll
    for (int p = 0; p < 5; ++p) {
      const int l = l5 + p;
      const int snew = (p + 4) % 5;
#pragma unroll
      for (int j = 0; j < 6; ++j) cw[j][snew] = cp[(grp * 6 + j) * LP + l + 4];
      float sk[5];
#pragma unroll
      for (int k = 0; k < K; ++k) sk[k] = sa[(l + k) * (CT * K) + clane * K + k];
      const bool live = (l < A + K - 1);
#pragma unroll
      for (int j = 0; j < 6; ++j) {
        float zv = 0.f;
#pragma unroll
        for (int k = 0; k < K; ++k) zv += cw[j][(p + k) % 5] * sk[k];
        if (live) best[j] = fmaxf(best[j], zv);
      }
    }
  }
  const float bc = bias[ct * CT + clane];
  float s = 0.f;
#pragma unroll
  for (int j = 0; j < 6; ++j) s += fmaxf(best[j] + bc, 0.f);
  red[grp * CT + clane] = s;
  __syncthreads();
  if (tid < CT) {
    float tot = 0.f;
#pragma unroll
    for (int g = 0; g < 8; ++g) tot += red[g * CT + tid];
    pbar[(size_t)b * C + ct * CT + tid] = tot * (1.0f / Q);
  }
}

// ---------------------------------------------------------------------------
// batched FC (z selects triple)
// ---------------------------------------------------------------------------
__global__ void fc_k(const float* __restrict__ pooled, const float* __restrict__ pbar,
                     const float* __restrict__ smW, const float* __restrict__ smb,
                     const float* __restrict__ ctxW, const float* __restrict__ ctxb,
                     float* __restrict__ acnn, float* __restrict__ bcnn,
                     float* __restrict__ attnf) {
  __shared__ float row[C];
  const int z = blockIdx.z;
  const float* in = (z == 0) ? pooled : (z == 1) ? pooled + (size_t)B * C : pbar;
  const float* Wm = (z == 2) ? ctxW : smW;
  const float* bs = (z == 2) ? ctxb : smb;
  float* out = (z == 0) ? acnn : (z == 1) ? bcnn : attnf;
  const int n = blockIdx.x;
  const int h = blockIdx.y * 256 + threadIdx.x;
  for (int c = threadIdx.x; c < C; c += 256) row[c] = in[(size_t)n * C + c];
  __syncthreads();
  float acc = bs[h];
  const float* w = Wm + (size_t)h * C;
  for (int c = 0; c < C; ++c) acc += row[c] * w[c];
  out[(size_t)n * H + h] = acc;
}

// transpose proj_w [P][3H] -> projT [3H][P]
__global__ void tpose_k(const float* __restrict__ in, float* __restrict__ outT) {
  __shared__ float tile[32][33];
  const int j0 = blockIdx.x * 32, p0 = blockIdx.y * 32;
  const int tx = threadIdx.x, ty = threadIdx.y;
  for (int i = ty; i < 32; i += 8) tile[i][tx] = in[(size_t)(p0 + i) * (3 * H) + j0 + tx];
  __syncthreads();
  for (int i = ty; i < 32; i += 8) outT[(size_t)(j0 + i) * P + p0 + tx] = tile[tx][i];
}

// comb[b,p] = proj_b[p] + cat[b,:] . projT[:,p]
__global__ void proj_k(const float* __restrict__ acnn, const float* __restrict__ bcnn,
                       const float* __restrict__ attn, const float* __restrict__ WT,
                       const float* __restrict__ bias, float* __restrict__ comb) {
  __shared__ float cat[3 * H];
  const int b = blockIdx.x;
  const int p = threadIdx.x;
  cat[p] = acnn[(size_t)b * H + p];
  cat[H + p] = bcnn[(size_t)b * H + p];
  cat[2 * H + p] = attn[(size_t)b * H + p];
  __syncthreads();
  float acc = bias[p];
  for (int j = 0; j < 3 * H; ++j) acc += cat[j] * WT[(size_t)j * P + p];
  comb[(size_t)b * P + p] = acc;
}

// batchnorm(train) + tanh + final FC
__global__ void bnout_k(const float* __restrict__ comb, const float* __restrict__ gamma,
                        const float* __restrict__ beta, const float* __restrict__ out_w,
                        const float* __restrict__ out_b, float* __restrict__ out) {
  __shared__ float t[B][P];
  const int p = threadIdx.x;
  float v[B];
  float mu = 0.f;
#pragma unroll
  for (int r = 0; r < B; ++r) { v[r] = comb[(size_t)r * P + p]; mu += v[r]; }
  mu *= (1.0f / B);
  float var = 0.f;
#pragma unroll
  for (int r = 0; r < B; ++r) { float d = v[r] - mu; var += d * d; }
  const float inv = rsqrtf(var * (1.0f / B) + EPS_BN);
  const float g = gamma[p], be = beta[p];
#pragma unroll
  for (int r = 0; r < B; ++r) t[r][p] = tanhf((v[r] - mu) * inv * g + be);
  __syncthreads();
  const int o = p >> 3, lane8 = p & 7;
  const int bb = o >> 1, cl = o & 1;
  float acc = 0.f;
  for (int j = lane8; j < P; j += 8) acc += t[bb][j] * out_w[cl * P + j];
#pragma unroll
  for (int off = 4; off; off >>= 1) acc += __shfl_down(acc, off);
  if (lane8 == 0) out[bb * NCLS + cl] = acc + out_b[cl];
}

extern "C" void kernel_launch(void* const* d_in, const int* in_sizes, int n_in,
                              void* d_out, int out_size, void* d_ws, size_t ws_size,
                              hipStream_t stream) {
  const float* q       = (const float*)d_in[0];
  const float* a       = (const float*)d_in[1];
  const float* sm_w    = (const float*)d_in[2];
  const float* sm_b    = (const float*)d_in[3];
  const float* sm_fcw  = (const float*)d_in[4];
  const float* sm_fcb  = (const float*)d_in[5];
  const float* ctx_w   = (const float*)d_in[6];
  const float* ctx_b   = (const float*)d_in[7];
  const float* ctx_fcw = (const float*)d_in[8];
  const float* ctx_fcb = (const float*)d_in[9];
  const float* proj_w  = (const float*)d_in[10];
  const float* proj_b  = (const float*)d_in[11];
  const float* gamma   = (const float*)d_in[12];
  const float* beta    = (const float*)d_in[13];
  const float* out_w   = (const float*)d_in[14];
  const float* out_b   = (const float*)d_in[15];

  float* ws = (float*)d_ws;
  size_t off = 0;
  auto alloc = [&](size_t n) { float* p = ws + off; off += n; return p; };
  float* Sq     = alloc((size_t)M * CK);
  float* Sa_sm  = alloc((size_t)M * CK);
  float* Sa_ctx = alloc((size_t)M * CK);
  float* cosm   = alloc((size_t)B * Q * A);
  float* pooled = alloc((size_t)2 * B * C);
  float* pbar   = alloc((size_t)B * C);
  float* acnn   = alloc((size_t)B * H);
  float* bcnn   = alloc((size_t)B * H);
  float* attnf  = alloc((size_t)B * H);
  float* projT  = alloc((size_t)3 * H * P);
  float* comb   = alloc((size_t)B * P);
  short* qb     = (short*)alloc((size_t)M * KP / 2);
  short* ab     = (short*)alloc((size_t)M * KP / 2);
  short* smb2   = (short*)alloc((size_t)CK * KP / 2);
  short* ctxb2  = (short*)alloc((size_t)CK * KP / 2);

  cvt_k<<<(2 * (M + CK) * 40) / 256, 256, 0, stream>>>(q, a, sm_w, ctx_w, qb, ab, smb2, ctxb2);
  gemm_mfma<<<dim3(CK / 128, M / 128, 3), 256, 0, stream>>>(qb, ab, smb2, ctxb2, Sq, Sa_sm, Sa_ctx);
  cos_k<<<B * Q, 64, 0, stream>>>(q, a, cosm);
  tpose_k<<<dim3(3 * H / 32, P / 32), dim3(32, 8), 0, stream>>>(proj_w, projT);

  smpool_k<<<dim3(C / CT, 2 * B), 256, 0, stream>>>(Sq, Sa_sm, sm_b, pooled);
  ctxpool_k<<<dim3(C / CT, B), 256, 0, stream>>>(Sa_ctx, cosm, ctx_b, pbar);

  fc_k<<<dim3(B, H / 256, 3), 256, 0, stream>>>(pooled, pbar, sm_fcw, sm_fcb,
                                                ctx_fcw, ctx_fcb, acnn, bcnn, attnf);
  proj_k<<<B, P, 0, stream>>>(acnn, bcnn, attnf, projT, proj_b, comb);
  bnout_k<<<1, P, 0, stream>>>(comb, gamma, beta, out_w, out_b, (float*)d_out);
}

// Round 4
// 165.132 us; speedup vs baseline: 3.3240x; 1.0233x over previous
//
#include <hip/hip_runtime.h>
#include <math.h>
#include <stdint.h>

namespace {
constexpr int B = 32, Q = 48, A = 48, D = 300;
constexpr int C = 512, K = 5, H = 512, P = 512, NCLS = 2;
constexpr int CK = C * K;         // 2560
constexpr int M = B * Q;          // 1536 rows for every GEMM
constexpr int KP = 320;           // K padded for bf16 MFMA
constexpr int CT = 32;            // c-tile for pooling kernels
constexpr int LP = 60;            // padded position axis
constexpr int LOUT = 52;          // conv output length, = 13 chunks of 4
constexpr float EPS_COS = 1e-6f, EPS_BN = 1e-5f;
}
using short8 = __attribute__((ext_vector_type(8))) short;
using f32x4  = __attribute__((ext_vector_type(4))) float;

__device__ inline short f2bf(float v) {
  uint32_t u = __builtin_bit_cast(uint32_t, v);
  return (short)((u + 0x7fffu + ((u >> 16) & 1u)) >> 16);  // RNE
}
__device__ inline float bf2f(short s) {
  uint32_t u = ((uint32_t)(uint16_t)s) << 16;
  return __builtin_bit_cast(float, u);
}

// ---------------------------------------------------------------------------
// fp32 -> bf16 with zero-pad K: 300 -> 320 (GEMM inputs).
// ---------------------------------------------------------------------------
__global__ void cvt_k(const float* __restrict__ q, const float* __restrict__ a,
                      const float* __restrict__ smw, const float* __restrict__ ctxw,
                      short* __restrict__ qb, short* __restrict__ ab,
                      short* __restrict__ smb, short* __restrict__ ctxb) {
  const int idx = blockIdx.x * 256 + threadIdx.x;
  const int row = idx / 40, ch = idx - row * 40;
  const float* src; short* dst; int r;
  if (row < M)            { src = q;    dst = qb;   r = row; }
  else if (row < 2 * M)   { src = a;    dst = ab;   r = row - M; }
  else if (row < 2*M+CK)  { src = smw;  dst = smb;  r = row - 2 * M; }
  else                    { src = ctxw; dst = ctxb; r = row - 2 * M - CK; }
  short tmp[8];
#pragma unroll
  for (int e = 0; e < 8; ++e) {
    const int k = ch * 8 + e;
    tmp[e] = (k < D) ? f2bf(src[(size_t)r * D + k]) : (short)0;
  }
  *(int4*)&dst[(size_t)r * KP + ch * 8] = *(const int4*)tmp;
}

// ---------------------------------------------------------------------------
// Batched NT GEMM, bf16 in, bf16 OUT (fp32 accum): Out[m,n]=sum_d X[m,d]W[n,d]
// 128x128 tile, 4 waves 2x2, 16x16x32 MFMA, XOR-swizzled LDS, prefetch.
// Epilogue: acc -> bf16 -> swizzled LDS tile -> contiguous dwordx4 stores.
// ---------------------------------------------------------------------------
__global__ void __launch_bounds__(256)
gemm_mfma(const short* __restrict__ qb, const short* __restrict__ ab,
          const short* __restrict__ smb, const short* __restrict__ ctxb,
          short* __restrict__ Sq, short* __restrict__ Sa_sm, short* __restrict__ Sa_ctx) {
  const int z = blockIdx.z;
  const short* X = (z == 0) ? qb : ab;
  const short* W = (z == 2) ? ctxb : smb;
  short* Out = (z == 0) ? Sq : (z == 1) ? Sa_sm : Sa_ctx;

  __shared__ short lds[2 * 128 * 64];  // As|Bs during K-loop; Cs in epilogue
  short* As = lds;
  short* Bs = lds + 128 * 64;
  const int tid = threadIdx.x, lane = tid & 63, wv = tid >> 6;
  const int wr = wv >> 1, wc = wv & 1;
  const int row0 = blockIdx.y * 128, col0 = blockIdx.x * 128;

  int rS[4], jS[4];
#pragma unroll
  for (int i = 0; i < 4; ++i) { int c = i * 256 + tid; rS[i] = c >> 3; jS[i] = c & 7; }

  int4 pA[4], pB[4];
  auto issue = [&](int ks) {
#pragma unroll
    for (int i = 0; i < 4; ++i) {
      pA[i] = *(const int4*)(X + (size_t)(row0 + rS[i]) * KP + ks * 64 + jS[i] * 8);
      pB[i] = *(const int4*)(W + (size_t)(col0 + rS[i]) * KP + ks * 64 + jS[i] * 8);
    }
  };

  f32x4 acc[4][4];
#pragma unroll
  for (int mi = 0; mi < 4; ++mi)
#pragma unroll
    for (int ni = 0; ni < 4; ++ni) acc[mi][ni] = f32x4{0.f, 0.f, 0.f, 0.f};

  issue(0);
  for (int ks = 0; ks < KP / 64; ++ks) {
    __syncthreads();
#pragma unroll
    for (int i = 0; i < 4; ++i) {
      const int soff = rS[i] * 64 + (jS[i] ^ (rS[i] & 7)) * 8;
      *(int4*)&As[soff] = pA[i];
      *(int4*)&Bs[soff] = pB[i];
    }
    if (ks < KP / 64 - 1) issue(ks + 1);
    __syncthreads();
#pragma unroll
    for (int kk = 0; kk < 2; ++kk) {
      const int kbase = kk * 32 + (lane >> 4) * 8;
      const int swz = (lane & 7) << 3;
      short8 af[4], bf[4];
#pragma unroll
      for (int mi = 0; mi < 4; ++mi) {
        const int rowa = wr * 64 + mi * 16 + (lane & 15);
        const int rowb = wc * 64 + mi * 16 + (lane & 15);
        af[mi] = *(const short8*)&As[rowa * 64 + (kbase ^ swz)];
        bf[mi] = *(const short8*)&Bs[rowb * 64 + (kbase ^ swz)];
      }
#pragma unroll
      for (int mi = 0; mi < 4; ++mi)
#pragma unroll
        for (int ni = 0; ni < 4; ++ni)
          acc[mi][ni] = __builtin_amdgcn_mfma_f32_16x16x32_bf16(af[mi], bf[ni], acc[mi][ni], 0, 0, 0);
    }
  }
  // ---- epilogue: bf16 via swizzled LDS transpose, contiguous 16B stores ----
  __syncthreads();
  short* Cs = lds;  // 128x128 shorts = 32 KB
  const int orow = (lane >> 4) * 4, ocol = lane & 15;
#pragma unroll
  for (int mi = 0; mi < 4; ++mi)
#pragma unroll
    for (int ni = 0; ni < 4; ++ni) {
      const int col = wc * 64 + ni * 16 + ocol;
#pragma unroll
      for (int r = 0; r < 4; ++r) {
        const int row = wr * 64 + mi * 16 + orow + r;
        Cs[row * 128 + (col ^ ((row & 15) << 3))] = f2bf(acc[mi][ni][r]);
      }
    }
  __syncthreads();
#pragma unroll
  for (int it = 0; it < 8; ++it) {
    const int row = it * 16 + (tid >> 4);
    const int cb = (tid & 15) * 8;
    const short8 v = *(const short8*)&Cs[row * 128 + (cb ^ ((row & 15) << 3))];
    *(short8*)&Out[(size_t)(row0 + row) * CK + col0 + cb] = v;
  }
}

// ---------------------------------------------------------------------------
// cosine similarity, norms fused, float4.  block = (b,qi), 64 threads.
// ---------------------------------------------------------------------------
__global__ void cos_k(const float* __restrict__ q, const float* __restrict__ a,
                      float* __restrict__ cosm) {
  __shared__ float4 qrow[75];
  __shared__ float qn_sh;
  const int bq = blockIdx.x;
  const int b = bq / Q;
  const int tid = threadIdx.x;
  const float4* qp = (const float4*)(q + (size_t)bq * D);
  float qsq = 0.f;
  for (int i = tid; i < 75; i += 64) {
    float4 v = qp[i]; qrow[i] = v;
    qsq += v.x * v.x + v.y * v.y + v.z * v.z + v.w * v.w;
  }
#pragma unroll
  for (int off = 32; off; off >>= 1) qsq += __shfl_down(qsq, off);
  if (tid == 0) qn_sh = sqrtf(qsq);
  __syncthreads();
  if (tid < A) {
    const float4* ap = (const float4*)(a + ((size_t)b * A + tid) * D);
    float dot = 0.f, asq = 0.f;
    for (int i = 0; i < 75; ++i) {
      float4 av = ap[i], qv = qrow[i];
      dot += qv.x * av.x + qv.y * av.y + qv.z * av.z + qv.w * av.w;
      asq += av.x * av.x + av.y * av.y + av.z * av.z + av.w * av.w;
    }
    float den = fmaxf(qn_sh * sqrtf(asq), EPS_COS);
    cosm[(size_t)bq * A + tid] = dot / den;
  }
}

// ---------------------------------------------------------------------------
// smpool: pooled[n,c] = relu(bias[c] + max_l sum_k S[n,l+k-4,c,k]); S bf16.
// Chunked (13 x 4 l's), batched LDS reads.
// ---------------------------------------------------------------------------
__global__ void smpool_k(const short* __restrict__ Sq, const short* __restrict__ Sa,
                         const float* __restrict__ bias, float* __restrict__ pooled) {
  __shared__ float sa[LP * CT * K];  // 38.4 KB
  __shared__ float red[8 * CT];
  const int n = blockIdx.y, ct = blockIdx.x, tid = threadIdx.x;
  const short* S = (n < B) ? Sq : Sa;
  const int nn = (n < B) ? n : n - B;

  float4* saz = (float4*)sa;
  for (int i = tid; i < LP * CT * K / 4; i += 256) saz[i] = float4{0.f, 0.f, 0.f, 0.f};
  __syncthreads();
  for (int i = tid; i < A * 20; i += 256) {   // 48 rows x 20 short8 chunks
    const int pos = i / 20, cc = i % 20;
    short8 v = *(const short8*)&S[((size_t)nn * A + pos) * CK + ct * 160 + cc * 8];
    float4 lo = {bf2f(v[0]), bf2f(v[1]), bf2f(v[2]), bf2f(v[3])};
    float4 hi = {bf2f(v[4]), bf2f(v[5]), bf2f(v[6]), bf2f(v[7])};
    *(float4*)&sa[(pos + 4) * 160 + cc * 8] = lo;
    *(float4*)&sa[(pos + 4) * 160 + cc * 8 + 4] = hi;
  }
  __syncthreads();

  const int clane = tid & 31, part = tid >> 5;
  float best = -1e30f;
  for (int ch = part; ch < 13; ch += 8) {
    float sk[4][5];
#pragma unroll
    for (int p = 0; p < 4; ++p)
#pragma unroll
      for (int k = 0; k < K; ++k)
        sk[p][k] = sa[(4 * ch + p + k) * 160 + clane * 5 + k];
#pragma unroll
    for (int p = 0; p < 4; ++p) {
      float zv = sk[p][0] + sk[p][1] + sk[p][2] + sk[p][3] + sk[p][4];
      best = fmaxf(best, zv);
    }
  }
  red[part * CT + clane] = best;
  __syncthreads();
  if (tid < CT) {
    float m = red[tid];
#pragma unroll
    for (int g = 1; g < 8; ++g) m = fmaxf(m, red[g * CT + tid]);
    pooled[(size_t)n * C + ct * CT + tid] = fmaxf(m + bias[ct * CT + tid], 0.f);
  }
}

// ---------------------------------------------------------------------------
// ctxpool + mean over q': chunked, dep-chain-free inner loop. S bf16.
// 256 thr = 8 q'-groups x 32 c-lanes; 6 q' per thread.
// ---------------------------------------------------------------------------
__global__ void ctxpool_k(const short* __restrict__ Sa, const float* __restrict__ cosm,
                          const float* __restrict__ bias, float* __restrict__ pbar) {
  __shared__ float sa[LP * CT * K];   // 38.4 KB
  __shared__ float cp3[Q * 72];       // 13.5 KB, cos[q,pos] at [q][4+pos]
  __shared__ float red[8 * CT];
  const int b = blockIdx.y, ct = blockIdx.x, tid = threadIdx.x;

  float4* saz = (float4*)sa;
  for (int i = tid; i < LP * CT * K / 4; i += 256) saz[i] = float4{0.f, 0.f, 0.f, 0.f};
  float4* cpz = (float4*)cp3;
  for (int i = tid; i < Q * 18; i += 256) cpz[i] = float4{0.f, 0.f, 0.f, 0.f};
  __syncthreads();
  for (int i = tid; i < A * 20; i += 256) {
    const int pos = i / 20, cc = i % 20;
    short8 v = *(const short8*)&Sa[((size_t)b * A + pos) * CK + ct * 160 + cc * 8];
    float4 lo = {bf2f(v[0]), bf2f(v[1]), bf2f(v[2]), bf2f(v[3])};
    float4 hi = {bf2f(v[4]), bf2f(v[5]), bf2f(v[6]), bf2f(v[7])};
    *(float4*)&sa[(pos + 4) * 160 + cc * 8] = lo;
    *(float4*)&sa[(pos + 4) * 160 + cc * 8 + 4] = hi;
  }
  for (int i = tid; i < Q * 12; i += 256) {   // cos rows as float4
    const int qi = i / 12, t = i % 12;
    float4 v = *(const float4*)&cosm[((size_t)b * Q + qi) * A + t * 4];
    *(float4*)&cp3[qi * 72 + 4 + t * 4] = v;
  }
  __syncthreads();

  const int clane = tid & 31, grp = tid >> 5;
  float best[6];
#pragma unroll
  for (int j = 0; j < 6; ++j) best[j] = -1e30f;

  for (int ch = 0; ch < 13; ++ch) {
    float cw[6][8];
#pragma unroll
    for (int j = 0; j < 6; ++j) {
      const float4 a0 = *(const float4*)&cp3[(grp * 6 + j) * 72 + 4 * ch];
      const float4 a1 = *(const float4*)&cp3[(grp * 6 + j) * 72 + 4 * ch + 4];
      cw[j][0] = a0.x; cw[j][1] = a0.y; cw[j][2] = a0.z; cw[j][3] = a0.w;
      cw[j][4] = a1.x; cw[j][5] = a1.y; cw[j][6] = a1.z; cw[j][7] = a1.w;
    }
    float sk[4][5];
#pragma unroll
    for (int p = 0; p < 4; ++p)
#pragma unroll
      for (int k = 0; k < K; ++k)
        sk[p][k] = sa[(4 * ch + p + k) * 160 + clane * 5 + k];
#pragma unroll
    for (int p = 0; p < 4; ++p)
#pragma unroll
      for (int j = 0; j < 6; ++j) {
        float zv = 0.f;
#pragma unroll
        for (int k = 0; k < K; ++k) zv += cw[j][p + k] * sk[p][k];
        best[j] = fmaxf(best[j], zv);
      }
  }
  const float bc = bias[ct * CT + clane];
  float s = 0.f;
#pragma unroll
  for (int j = 0; j < 6; ++j) s += fmaxf(best[j] + bc, 0.f);
  red[grp * CT + clane] = s;
  __syncthreads();
  if (tid < CT) {
    float tot = 0.f;
#pragma unroll
    for (int g = 0; g < 8; ++g) tot += red[g * CT + tid];
    pbar[(size_t)b * C + ct * CT + tid] = tot * (1.0f / Q);
  }
}

// ---------------------------------------------------------------------------
// batched FC (z selects triple)
// ---------------------------------------------------------------------------
__global__ void fc_k(const float* __restrict__ pooled, const float* __restrict__ pbar,
                     const float* __restrict__ smW, const float* __restrict__ smb,
                     const float* __restrict__ ctxW, const float* __restrict__ ctxb,
                     float* __restrict__ acnn, float* __restrict__ bcnn,
                     float* __restrict__ attnf) {
  __shared__ float row[C];
  const int z = blockIdx.z;
  const float* in = (z == 0) ? pooled : (z == 1) ? pooled + (size_t)B * C : pbar;
  const float* Wm = (z == 2) ? ctxW : smW;
  const float* bs = (z == 2) ? ctxb : smb;
  float* out = (z == 0) ? acnn : (z == 1) ? bcnn : attnf;
  const int n = blockIdx.x;
  const int h = blockIdx.y * 256 + threadIdx.x;
  for (int c = threadIdx.x; c < C; c += 256) row[c] = in[(size_t)n * C + c];
  __syncthreads();
  float acc = bs[h];
  const float* w = Wm + (size_t)h * C;
  for (int c = 0; c < C; ++c) acc += row[c] * w[c];
  out[(size_t)n * H + h] = acc;
}

// transpose proj_w [P][3H] -> projT [3H][P]
__global__ void tpose_k(const float* __restrict__ in, float* __restrict__ outT) {
  __shared__ float tile[32][33];
  const int j0 = blockIdx.x * 32, p0 = blockIdx.y * 32;
  const int tx = threadIdx.x, ty = threadIdx.y;
  for (int i = ty; i < 32; i += 8) tile[i][tx] = in[(size_t)(p0 + i) * (3 * H) + j0 + tx];
  __syncthreads();
  for (int i = ty; i < 32; i += 8) outT[(size_t)(j0 + i) * P + p0 + tx] = tile[tx][i];
}

// comb[b,p] = proj_b[p] + cat[b,:] . projT[:,p]
__global__ void proj_k(const float* __restrict__ acnn, const float* __restrict__ bcnn,
                       const float* __restrict__ attn, const float* __restrict__ WT,
                       const float* __restrict__ bias, float* __restrict__ comb) {
  __shared__ float cat[3 * H];
  const int b = blockIdx.x;
  const int p = threadIdx.x;
  cat[p] = acnn[(size_t)b * H + p];
  cat[H + p] = bcnn[(size_t)b * H + p];
  cat[2 * H + p] = attn[(size_t)b * H + p];
  __syncthreads();
  float acc = bias[p];
  for (int j = 0; j < 3 * H; ++j) acc += cat[j] * WT[(size_t)j * P + p];
  comb[(size_t)b * P + p] = acc;
}

// batchnorm(train) + tanh + final FC
__global__ void bnout_k(const float* __restrict__ comb, const float* __restrict__ gamma,
                        const float* __restrict__ beta, const float* __restrict__ out_w,
                        const float* __restrict__ out_b, float* __restrict__ out) {
  __shared__ float t[B][P];
  const int p = threadIdx.x;
  float v[B];
  float mu = 0.f;
#pragma unroll
  for (int r = 0; r < B; ++r) { v[r] = comb[(size_t)r * P + p]; mu += v[r]; }
  mu *= (1.0f / B);
  float var = 0.f;
#pragma unroll
  for (int r = 0; r < B; ++r) { float d = v[r] - mu; var += d * d; }
  const float inv = rsqrtf(var * (1.0f / B) + EPS_BN);
  const float g = gamma[p], be = beta[p];
#pragma unroll
  for (int r = 0; r < B; ++r) t[r][p] = tanhf((v[r] - mu) * inv * g + be);
  __syncthreads();
  const int o = p >> 3, lane8 = p & 7;
  const int bb = o >> 1, cl = o & 1;
  float acc = 0.f;
  for (int j = lane8; j < P; j += 8) acc += t[bb][j] * out_w[cl * P + j];
#pragma unroll
  for (int off = 4; off; off >>= 1) acc += __shfl_down(acc, off);
  if (lane8 == 0) out[bb * NCLS + cl] = acc + out_b[cl];
}

extern "C" void kernel_launch(void* const* d_in, const int* in_sizes, int n_in,
                              void* d_out, int out_size, void* d_ws, size_t ws_size,
                              hipStream_t stream) {
  const float* q       = (const float*)d_in[0];
  const float* a       = (const float*)d_in[1];
  const float* sm_w    = (const float*)d_in[2];
  const float* sm_b    = (const float*)d_in[3];
  const float* sm_fcw  = (const float*)d_in[4];
  const float* sm_fcb  = (const float*)d_in[5];
  const float* ctx_w   = (const float*)d_in[6];
  const float* ctx_b   = (const float*)d_in[7];
  const float* ctx_fcw = (const float*)d_in[8];
  const float* ctx_fcb = (const float*)d_in[9];
  const float* proj_w  = (const float*)d_in[10];
  const float* proj_b  = (const float*)d_in[11];
  const float* gamma   = (const float*)d_in[12];
  const float* beta    = (const float*)d_in[13];
  const float* out_w   = (const float*)d_in[14];
  const float* out_b   = (const float*)d_in[15];

  float* ws = (float*)d_ws;
  size_t off = 0;
  auto alloc = [&](size_t n) { float* p = ws + off; off += n; return p; };
  short* Sq     = (short*)alloc((size_t)M * CK / 2);   // bf16 S matrices
  short* Sa_sm  = (short*)alloc((size_t)M * CK / 2);
  short* Sa_ctx = (short*)alloc((size_t)M * CK / 2);
  float* cosm   = alloc((size_t)B * Q * A);
  float* pooled = alloc((size_t)2 * B * C);
  float* pbar   = alloc((size_t)B * C);
  float* acnn   = alloc((size_t)B * H);
  float* bcnn   = alloc((size_t)B * H);
  float* attnf  = alloc((size_t)B * H);
  float* projT  = alloc((size_t)3 * H * P);
  float* comb   = alloc((size_t)B * P);
  short* qb     = (short*)alloc((size_t)M * KP / 2);
  short* ab     = (short*)alloc((size_t)M * KP / 2);
  short* smb2   = (short*)alloc((size_t)CK * KP / 2);
  short* ctxb2  = (short*)alloc((size_t)CK * KP / 2);

  cvt_k<<<(2 * (M + CK) * 40) / 256, 256, 0, stream>>>(q, a, sm_w, ctx_w, qb, ab, smb2, ctxb2);
  cos_k<<<B * Q, 64, 0, stream>>>(q, a, cosm);
  tpose_k<<<dim3(3 * H / 32, P / 32), dim3(32, 8), 0, stream>>>(proj_w, projT);
  gemm_mfma<<<dim3(CK / 128, M / 128, 3), 256, 0, stream>>>(qb, ab, smb2, ctxb2, Sq, Sa_sm, Sa_ctx);

  smpool_k<<<dim3(C / CT, 2 * B), 256, 0, stream>>>(Sq, Sa_sm, sm_b, pooled);
  ctxpool_k<<<dim3(C / CT, B), 256, 0, stream>>>(Sa_ctx, cosm, ctx_b, pbar);

  fc_k<<<dim3(B, H / 256, 3), 256, 0, stream>>>(pooled, pbar, sm_fcw, sm_fcb,
                                                ctx_fcw, ctx_fcb, acnn, bcnn, attnf);
  proj_k<<<B, P, 0, stream>>>(acnn, bcnn, attnf, projT, proj_b, comb);
  bnout_k<<<1, P, 0, stream>>>(comb, gamma, beta, out_w, out_b, (float*)d_out);
}

// Round 5
// 151.285 us; speedup vs baseline: 3.6283x; 1.0915x over previous
//
#include <hip/hip_runtime.h>
#include <math.h>
#include <stdint.h>

namespace {
constexpr int B = 32, Q = 48, A = 48, D = 300;
constexpr int C = 512, K = 5, H = 512, P = 512, NCLS = 2;
constexpr int CK = C * K;         // 2560
constexpr int M = B * Q;          // 1536
constexpr int KP = 320;           // K padded for bf16 MFMA
constexpr int CT = 32;            // c-tile for pooling kernels
constexpr int LP = 60;            // padded position axis
constexpr float EPS_COS = 1e-6f, EPS_BN = 1e-5f;
constexpr int NCVT = (2 * (M + CK) * 40) / 256;  // 1280 blocks
constexpr int NTP  = (3 * H / 32) * (P / 32);    // 768 blocks
constexpr int NCOS = M / 4;                      // 384 blocks
constexpr int NJ = 8;                            // proj j-chunks (1536/192)
}
using short8 = __attribute__((ext_vector_type(8))) short;
using f32x4  = __attribute__((ext_vector_type(4))) float;

__device__ inline short f2bf(float v) {
  uint32_t u = __builtin_bit_cast(uint32_t, v);
  return (short)((u + 0x7fffu + ((u >> 16) & 1u)) >> 16);  // RNE
}
__device__ inline float bf2f(short s) {
  uint32_t u = ((uint32_t)(uint16_t)s) << 16;
  return __builtin_bit_cast(float, u);
}

// ---------------------------------------------------------------------------
// prep: [0,NCVT) fp32->bf16 pad-to-320 | [.,+NTP) proj_w transpose | cos sim
// ---------------------------------------------------------------------------
__global__ void prep_k(const float* __restrict__ q, const float* __restrict__ a,
                       const float* __restrict__ smw, const float* __restrict__ ctxw,
                       const float* __restrict__ projw,
                       short* __restrict__ qb, short* __restrict__ ab,
                       short* __restrict__ smb, short* __restrict__ ctxb,
                       float* __restrict__ projT, float* __restrict__ cosm) {
  __shared__ float tile[32][33];
  __shared__ float4 qrow4[300];
  const int blk = blockIdx.x, tid = threadIdx.x;
  if (blk < NCVT) {
    const int idx = blk * 256 + tid;
    const int row = idx / 40, ch = idx - row * 40;
    const float* src; short* dst; int r;
    if (row < M)              { src = q;    dst = qb;   r = row; }
    else if (row < 2 * M)     { src = a;    dst = ab;   r = row - M; }
    else if (row < 2 * M + CK){ src = smw;  dst = smb;  r = row - 2 * M; }
    else                      { src = ctxw; dst = ctxb; r = row - 2 * M - CK; }
    short tmp[8];
#pragma unroll
    for (int e = 0; e < 8; ++e) {
      const int k = ch * 8 + e;
      tmp[e] = (k < D) ? f2bf(src[(size_t)r * D + k]) : (short)0;
    }
    *(int4*)&dst[(size_t)r * KP + ch * 8] = *(const int4*)tmp;
  } else if (blk < NCVT + NTP) {
    const int b2 = blk - NCVT;
    const int j0 = (b2 % 48) * 32, p0 = (b2 / 48) * 32;
    const int tx = tid & 31, ty = tid >> 5;
    for (int i = ty; i < 32; i += 8)
      tile[i][tx] = projw[(size_t)(p0 + i) * (3 * H) + j0 + tx];
    __syncthreads();
    for (int i = ty; i < 32; i += 8)
      projT[(size_t)(j0 + i) * P + p0 + tx] = tile[tx][i];
  } else {
    const int b3 = blk - NCVT - NTP;
    const int qq = b3 * 4;          // 4 q-rows per block, same b (48 % 4 == 0)
    const int b = qq / Q;
    const float4* qp4 = (const float4*)(q + (size_t)qq * D);
    for (int i = tid; i < 300; i += 256) qrow4[i] = qp4[i];
    __syncthreads();
    const int sub = tid >> 6, lane = tid & 63;
    float qsq = 0.f;
    for (int i = lane; i < 75; i += 64) {
      float4 v = qrow4[sub * 75 + i];
      qsq += v.x * v.x + v.y * v.y + v.z * v.z + v.w * v.w;
    }
#pragma unroll
    for (int off = 32; off; off >>= 1) qsq += __shfl_xor(qsq, off);
    const float qn = sqrtf(qsq);
    if (lane < A) {
      const float4* ap4 = (const float4*)(a + ((size_t)b * A + lane) * D);
      float dot = 0.f, asq = 0.f;
      for (int i = 0; i < 75; ++i) {
        float4 av = ap4[i], qv = qrow4[sub * 75 + i];
        dot += qv.x * av.x + qv.y * av.y + qv.z * av.z + qv.w * av.w;
        asq += av.x * av.x + av.y * av.y + av.z * av.z + av.w * av.w;
      }
      cosm[(size_t)(qq + sub) * A + lane] = dot / fmaxf(qn * sqrtf(asq), EPS_COS);
    }
  }
}

// ---------------------------------------------------------------------------
// Direct-from-L2 register MFMA GEMM. No staging LDS, no K-loop barriers.
// Each wave: independent 64x64 tile, 4x4 frags of 16x16x32, 1-deep prefetch.
// Epilogue: per-wave 8KB LDS transpose (XOR-swizzle) -> int4 stores.
// ---------------------------------------------------------------------------
__global__ void __launch_bounds__(256)
gemm_mfma(const short* __restrict__ qb, const short* __restrict__ ab,
          const short* __restrict__ smb, const short* __restrict__ ctxb,
          short* __restrict__ Sq, short* __restrict__ Sa_sm, short* __restrict__ Sa_ctx) {
  const int z = blockIdx.z;
  const short* X = (z == 0) ? qb : ab;
  const short* W = (z == 2) ? ctxb : smb;
  short* Out = (z == 0) ? Sq : (z == 1) ? Sa_sm : Sa_ctx;

  __shared__ short Cs[4][64 * 64];  // 32 KB, one 8KB region per wave
  const int tid = threadIdx.x, lane = tid & 63, wv = tid >> 6;
  const int wr = wv >> 1, wc = wv & 1;
  const int r16 = lane & 15, kq = lane >> 4;
  const size_t rowA0 = (size_t)blockIdx.y * 128 + wr * 64;
  const size_t colB0 = (size_t)blockIdx.x * 128 + wc * 64;
  const short* Xw = X + (rowA0 + r16) * KP + kq * 8;
  const short* Ww = W + (colB0 + r16) * KP + kq * 8;

  f32x4 acc[4][4];
#pragma unroll
  for (int mi = 0; mi < 4; ++mi)
#pragma unroll
    for (int ni = 0; ni < 4; ++ni) acc[mi][ni] = f32x4{0.f, 0.f, 0.f, 0.f};

  int4 cA[4], cB[4];
#pragma unroll
  for (int i = 0; i < 4; ++i) {
    cA[i] = *(const int4*)(Xw + i * 16 * KP);
    cB[i] = *(const int4*)(Ww + i * 16 * KP);
  }
#pragma unroll 1
  for (int ks = 0; ks < KP / 32; ++ks) {
    int4 nA[4], nB[4];
    if (ks < KP / 32 - 1) {
#pragma unroll
      for (int i = 0; i < 4; ++i) {
        nA[i] = *(const int4*)(Xw + i * 16 * KP + (ks + 1) * 32);
        nB[i] = *(const int4*)(Ww + i * 16 * KP + (ks + 1) * 32);
      }
    }
#pragma unroll
    for (int mi = 0; mi < 4; ++mi)
#pragma unroll
      for (int ni = 0; ni < 4; ++ni)
        acc[mi][ni] = __builtin_amdgcn_mfma_f32_16x16x32_bf16(
            __builtin_bit_cast(short8, cA[mi]),
            __builtin_bit_cast(short8, cB[ni]), acc[mi][ni], 0, 0, 0);
    if (ks < KP / 32 - 1) {
#pragma unroll
      for (int i = 0; i < 4; ++i) { cA[i] = nA[i]; cB[i] = nB[i]; }
    }
  }

  // per-wave epilogue (no __syncthreads: wave-private LDS region)
  short* cs = Cs[wv];
#pragma unroll
  for (int mi = 0; mi < 4; ++mi)
#pragma unroll
    for (int ni = 0; ni < 4; ++ni) {
      const int col = ni * 16 + r16;
#pragma unroll
      for (int r = 0; r < 4; ++r) {
        const int row = mi * 16 + kq * 4 + r;
        cs[row * 64 + (col ^ ((row & 7) << 3))] = f2bf(acc[mi][ni][r]);
      }
    }
#pragma unroll
  for (int it = 0; it < 8; ++it) {
    const int row = it * 8 + (lane >> 3);
    const int c8 = (lane & 7) * 8;
    const int4 v = *(const int4*)&cs[row * 64 + (c8 ^ ((row & 7) << 3))];
    *(int4*)&Out[(rowA0 + row) * CK + colB0 + c8] = v;
  }
}

// ---------------------------------------------------------------------------
// smpool: pooled[n,c] = relu(bias[c] + max_l sum_k S[n,l+k-4,c,k]); S bf16.
// ---------------------------------------------------------------------------
__global__ void smpool_k(const short* __restrict__ Sq, const short* __restrict__ Sa,
                         const float* __restrict__ bias, float* __restrict__ pooled) {
  __shared__ float sa[LP * CT * K];  // 38.4 KB
  __shared__ float red[8 * CT];
  const int n = blockIdx.y, ct = blockIdx.x, tid = threadIdx.x;
  const short* S = (n < B) ? Sq : Sa;
  const int nn = (n < B) ? n : n - B;

  float4* saz = (float4*)sa;
  for (int i = tid; i < LP * CT * K / 4; i += 256) saz[i] = float4{0.f, 0.f, 0.f, 0.f};
  __syncthreads();
  for (int i = tid; i < A * 20; i += 256) {
    const int pos = i / 20, cc = i % 20;
    const int4 v4 = *(const int4*)&S[((size_t)nn * A + pos) * CK + ct * 160 + cc * 8];
    const short8 v = __builtin_bit_cast(short8, v4);
    float4 lo = {bf2f(v[0]), bf2f(v[1]), bf2f(v[2]), bf2f(v[3])};
    float4 hi = {bf2f(v[4]), bf2f(v[5]), bf2f(v[6]), bf2f(v[7])};
    *(float4*)&sa[(pos + 4) * 160 + cc * 8] = lo;
    *(float4*)&sa[(pos + 4) * 160 + cc * 8 + 4] = hi;
  }
  __syncthreads();

  const int clane = tid & 31, part = tid >> 5;
  float best = -1e30f;
  for (int ch = part; ch < 13; ch += 8) {
    float sk[4][5];
#pragma unroll
    for (int p = 0; p < 4; ++p)
#pragma unroll
      for (int k = 0; k < K; ++k)
        sk[p][k] = sa[(4 * ch + p + k) * 160 + clane * 5 + k];
#pragma unroll
    for (int p = 0; p < 4; ++p) {
      float zv = sk[p][0] + sk[p][1] + sk[p][2] + sk[p][3] + sk[p][4];
      best = fmaxf(best, zv);
    }
  }
  red[part * CT + clane] = best;
  __syncthreads();
  if (tid < CT) {
    float m = red[tid];
#pragma unroll
    for (int g = 1; g < 8; ++g) m = fmaxf(m, red[g * CT + tid]);
    pooled[(size_t)n * C + ct * CT + tid] = fmaxf(m + bias[ct * CT + tid], 0.f);
  }
}

// ---------------------------------------------------------------------------
// ctxpool + mean over q'. S bf16. 8 q'-groups x 32 c-lanes, 6 q'/thread.
// ---------------------------------------------------------------------------
__global__ void ctxpool_k(const short* __restrict__ Sa, const float* __restrict__ cosm,
                          const float* __restrict__ bias, float* __restrict__ pbar) {
  __shared__ float sa[LP * CT * K];   // 38.4 KB
  __shared__ float cp3[Q * 72];       // 13.5 KB
  __shared__ float red[8 * CT];
  const int b = blockIdx.y, ct = blockIdx.x, tid = threadIdx.x;

  float4* saz = (float4*)sa;
  for (int i = tid; i < LP * CT * K / 4; i += 256) saz[i] = float4{0.f, 0.f, 0.f, 0.f};
  float4* cpz = (float4*)cp3;
  for (int i = tid; i < Q * 18; i += 256) cpz[i] = float4{0.f, 0.f, 0.f, 0.f};
  __syncthreads();
  for (int i = tid; i < A * 20; i += 256) {
    const int pos = i / 20, cc = i % 20;
    const int4 v4 = *(const int4*)&Sa[((size_t)b * A + pos) * CK + ct * 160 + cc * 8];
    const short8 v = __builtin_bit_cast(short8, v4);
    float4 lo = {bf2f(v[0]), bf2f(v[1]), bf2f(v[2]), bf2f(v[3])};
    float4 hi = {bf2f(v[4]), bf2f(v[5]), bf2f(v[6]), bf2f(v[7])};
    *(float4*)&sa[(pos + 4) * 160 + cc * 8] = lo;
    *(float4*)&sa[(pos + 4) * 160 + cc * 8 + 4] = hi;
  }
  for (int i = tid; i < Q * 12; i += 256) {
    const int qi = i / 12, t = i % 12;
    float4 v = *(const float4*)&cosm[((size_t)b * Q + qi) * A + t * 4];
    *(float4*)&cp3[qi * 72 + 4 + t * 4] = v;
  }
  __syncthreads();

  const int clane = tid & 31, grp = tid >> 5;
  float best[6];
#pragma unroll
  for (int j = 0; j < 6; ++j) best[j] = -1e30f;

  for (int ch = 0; ch < 13; ++ch) {
    float cw[6][8];
#pragma unroll
    for (int j = 0; j < 6; ++j) {
      const float4 a0 = *(const float4*)&cp3[(grp * 6 + j) * 72 + 4 * ch];
      const float4 a1 = *(const float4*)&cp3[(grp * 6 + j) * 72 + 4 * ch + 4];
      cw[j][0] = a0.x; cw[j][1] = a0.y; cw[j][2] = a0.z; cw[j][3] = a0.w;
      cw[j][4] = a1.x; cw[j][5] = a1.y; cw[j][6] = a1.z; cw[j][7] = a1.w;
    }
    float sk[4][5];
#pragma unroll
    for (int p = 0; p < 4; ++p)
#pragma unroll
      for (int k = 0; k < K; ++k)
        sk[p][k] = sa[(4 * ch + p + k) * 160 + clane * 5 + k];
#pragma unroll
    for (int p = 0; p < 4; ++p)
#pragma unroll
      for (int j = 0; j < 6; ++j) {
        float zv = 0.f;
#pragma unroll
        for (int k = 0; k < K; ++k) zv += cw[j][p + k] * sk[p][k];
        best[j] = fmaxf(best[j], zv);
      }
  }
  const float bc = bias[ct * CT + clane];
  float s = 0.f;
#pragma unroll
  for (int j = 0; j < 6; ++j) s += fmaxf(best[j] + bc, 0.f);
  red[grp * CT + clane] = s;
  __syncthreads();
  if (tid < CT) {
    float tot = 0.f;
#pragma unroll
    for (int g = 0; g < 8; ++g) tot += red[g * CT + tid];
    pbar[(size_t)b * C + ct * CT + tid] = tot * (1.0f / Q);
  }
}

// ---------------------------------------------------------------------------
// batched FC (z selects triple)
// ---------------------------------------------------------------------------
__global__ void fc_k(const float* __restrict__ pooled, const float* __restrict__ pbar,
                     const float* __restrict__ smW, const float* __restrict__ smb,
                     const float* __restrict__ ctxW, const float* __restrict__ ctxb,
                     float* __restrict__ acnn, float* __restrict__ bcnn,
                     float* __restrict__ attnf) {
  __shared__ float row[C];
  const int z = blockIdx.z;
  const float* in = (z == 0) ? pooled : (z == 1) ? pooled + (size_t)B * C : pbar;
  const float* Wm = (z == 2) ? ctxW : smW;
  const float* bs = (z == 2) ? ctxb : smb;
  float* out = (z == 0) ? acnn : (z == 1) ? bcnn : attnf;
  const int n = blockIdx.x;
  const int h = blockIdx.y * 256 + threadIdx.x;
  for (int c = threadIdx.x; c < C; c += 256) row[c] = in[(size_t)n * C + c];
  __syncthreads();
  float acc = bs[h];
  const float* w = Wm + (size_t)h * C;
  for (int c = 0; c < C; ++c) acc += row[c] * w[c];
  out[(size_t)n * H + h] = acc;
}

// ---------------------------------------------------------------------------
// proj, split 8-way over j: partial[g][b][p] = sum_{j in chunk g} cat[b,j]*WT[j,p]
// ---------------------------------------------------------------------------
__global__ void proj_k(const float* __restrict__ acnn, const float* __restrict__ bcnn,
                       const float* __restrict__ attnf, const float* __restrict__ WT,
                       float* __restrict__ partial) {
  __shared__ float cs[192];
  const int b = blockIdx.x, g = blockIdx.y, tid = threadIdx.x;
  const int js = g * 192;
  if (tid < 192) {
    const int j = js + tid;
    float v;
    if (j < H)          v = acnn[(size_t)b * H + j];
    else if (j < 2 * H) v = bcnn[(size_t)b * H + j - H];
    else                v = attnf[(size_t)b * H + j - 2 * H];
    cs[tid] = v;
  }
  __syncthreads();
  float a0 = 0.f, a1 = 0.f;
  for (int j = 0; j < 192; ++j) {
    const float c = cs[j];
    a0 += c * WT[(size_t)(js + j) * P + tid];
    a1 += c * WT[(size_t)(js + j) * P + tid + 256];
  }
  partial[((size_t)g * B + b) * P + tid] = a0;
  partial[((size_t)g * B + b) * P + tid + 256] = a1;
}

// ---------------------------------------------------------------------------
// partial-sum + bias + batchnorm(train) + tanh + final FC
// ---------------------------------------------------------------------------
__global__ void bnout_k(const float* __restrict__ partial, const float* __restrict__ proj_b,
                        const float* __restrict__ gamma, const float* __restrict__ beta,
                        const float* __restrict__ out_w, const float* __restrict__ out_b,
                        float* __restrict__ out) {
  __shared__ float t[B][P];
  const int p = threadIdx.x;
  const float pb = proj_b[p];
  float v[B];
  float mu = 0.f;
#pragma unroll
  for (int r = 0; r < B; ++r) {
    float s = pb;
#pragma unroll
    for (int g = 0; g < NJ; ++g) s += partial[((size_t)g * B + r) * P + p];
    v[r] = s;
    mu += s;
  }
  mu *= (1.0f / B);
  float var = 0.f;
#pragma unroll
  for (int r = 0; r < B; ++r) { float d = v[r] - mu; var += d * d; }
  const float inv = rsqrtf(var * (1.0f / B) + EPS_BN);
  const float g = gamma[p], be = beta[p];
#pragma unroll
  for (int r = 0; r < B; ++r) t[r][p] = tanhf((v[r] - mu) * inv * g + be);
  __syncthreads();
  const int o = p >> 3, lane8 = p & 7;
  const int bb = o >> 1, cl = o & 1;
  float acc = 0.f;
  for (int j = lane8; j < P; j += 8) acc += t[bb][j] * out_w[cl * P + j];
#pragma unroll
  for (int off = 4; off; off >>= 1) acc += __shfl_down(acc, off);
  if (lane8 == 0) out[bb * NCLS + cl] = acc + out_b[cl];
}

extern "C" void kernel_launch(void* const* d_in, const int* in_sizes, int n_in,
                              void* d_out, int out_size, void* d_ws, size_t ws_size,
                              hipStream_t stream) {
  const float* q       = (const float*)d_in[0];
  const float* a       = (const float*)d_in[1];
  const float* sm_w    = (const float*)d_in[2];
  const float* sm_b    = (const float*)d_in[3];
  const float* sm_fcw  = (const float*)d_in[4];
  const float* sm_fcb  = (const float*)d_in[5];
  const float* ctx_w   = (const float*)d_in[6];
  const float* ctx_b   = (const float*)d_in[7];
  const float* ctx_fcw = (const float*)d_in[8];
  const float* ctx_fcb = (const float*)d_in[9];
  const float* proj_w  = (const float*)d_in[10];
  const float* proj_b  = (const float*)d_in[11];
  const float* gamma   = (const float*)d_in[12];
  const float* beta    = (const float*)d_in[13];
  const float* out_w   = (const float*)d_in[14];
  const float* out_b   = (const float*)d_in[15];

  float* ws = (float*)d_ws;
  size_t off = 0;
  auto alloc = [&](size_t n) { float* p = ws + off; off += n; return p; };
  short* Sq     = (short*)alloc((size_t)M * CK / 2);
  short* Sa_sm  = (short*)alloc((size_t)M * CK / 2);
  short* Sa_ctx = (short*)alloc((size_t)M * CK / 2);
  float* cosm   = alloc((size_t)B * Q * A);
  float* pooled = alloc((size_t)2 * B * C);
  float* pbar   = alloc((size_t)B * C);
  float* acnn   = alloc((size_t)B * H);
  float* bcnn   = alloc((size_t)B * H);
  float* attnf  = alloc((size_t)B * H);
  float* projT  = alloc((size_t)3 * H * P);
  float* partial= alloc((size_t)NJ * B * P);
  short* qb     = (short*)alloc((size_t)M * KP / 2);
  short* ab     = (short*)alloc((size_t)M * KP / 2);
  short* smb2   = (short*)alloc((size_t)CK * KP / 2);
  short* ctxb2  = (short*)alloc((size_t)CK * KP / 2);

  prep_k<<<NCVT + NTP + NCOS, 256, 0, stream>>>(q, a, sm_w, ctx_w, proj_w,
                                                qb, ab, smb2, ctxb2, projT, cosm);
  gemm_mfma<<<dim3(CK / 128, M / 128, 3), 256, 0, stream>>>(qb, ab, smb2, ctxb2,
                                                            Sq, Sa_sm, Sa_ctx);
  smpool_k<<<dim3(C / CT, 2 * B), 256, 0, stream>>>(Sq, Sa_sm, sm_b, pooled);
  ctxpool_k<<<dim3(C / CT, B), 256, 0, stream>>>(Sa_ctx, cosm, ctx_b, pbar);
  fc_k<<<dim3(B, H / 256, 3), 256, 0, stream>>>(pooled, pbar, sm_fcw, sm_fcb,
                                                ctx_fcw, ctx_fcb, acnn, bcnn, attnf);
  proj_k<<<dim3(B, NJ), 256, 0, stream>>>(acnn, bcnn, attnf, projT, partial);
  bnout_k<<<1, P, 0, stream>>>(partial, proj_b, gamma, beta, out_w, out_b, (float*)d_out);
}

// Round 6
// 117.630 us; speedup vs baseline: 4.6663x; 1.2861x over previous
//
#include <hip/hip_runtime.h>
#include <math.h>
#include <stdint.h>

namespace {
constexpr int B = 32, Q = 48, A = 48, D = 300;
constexpr int C = 512, K = 5, H = 512, P = 512, NCLS = 2;
constexpr int CK = C * K;         // 2560
constexpr int M = B * Q;          // 1536
constexpr int KP = 320;           // K padded for bf16 MFMA
constexpr int CT = 32;            // c-tile for pooling kernels
constexpr int LP = 60;            // padded position axis
constexpr float EPS_COS = 1e-6f, EPS_BN = 1e-5f;
constexpr int NCVT = (2 * (M + CK) * 40) / 256;  // 1280 blocks
constexpr int NTP  = (3 * H / 32) * (P / 32);    // 768 blocks
constexpr int NCOS = M / 4;                      // 384 blocks
constexpr int NJ = 8;                            // proj j-chunks (1536/192)
}
using short8 = __attribute__((ext_vector_type(8))) short;
using f32x4  = __attribute__((ext_vector_type(4))) float;

__device__ inline short f2bf(float v) {
  uint32_t u = __builtin_bit_cast(uint32_t, v);
  return (short)((u + 0x7fffu + ((u >> 16) & 1u)) >> 16);  // RNE
}
__device__ inline float bf2f(short s) {
  uint32_t u = ((uint32_t)(uint16_t)s) << 16;
  return __builtin_bit_cast(float, u);
}

// ---------------------------------------------------------------------------
// prep: [0,NCVT) fp32->bf16 pad-to-320 | [.,+NTP) proj_w transpose | cos sim
// ---------------------------------------------------------------------------
__global__ void prep_k(const float* __restrict__ q, const float* __restrict__ a,
                       const float* __restrict__ smw, const float* __restrict__ ctxw,
                       const float* __restrict__ projw,
                       short* __restrict__ qb, short* __restrict__ ab,
                       short* __restrict__ smb, short* __restrict__ ctxb,
                       float* __restrict__ projT, float* __restrict__ cosm) {
  __shared__ float tile[32][33];
  __shared__ float4 qrow4[300];
  const int blk = blockIdx.x, tid = threadIdx.x;
  if (blk < NCVT) {
    const int idx = blk * 256 + tid;
    const int row = idx / 40, ch = idx - row * 40;
    const float* src; short* dst; int r;
    if (row < M)              { src = q;    dst = qb;   r = row; }
    else if (row < 2 * M)     { src = a;    dst = ab;   r = row - M; }
    else if (row < 2 * M + CK){ src = smw;  dst = smb;  r = row - 2 * M; }
    else                      { src = ctxw; dst = ctxb; r = row - 2 * M - CK; }
    short tmp[8];
#pragma unroll
    for (int e = 0; e < 8; ++e) {
      const int k = ch * 8 + e;
      tmp[e] = (k < D) ? f2bf(src[(size_t)r * D + k]) : (short)0;
    }
    *(int4*)&dst[(size_t)r * KP + ch * 8] = *(const int4*)tmp;
  } else if (blk < NCVT + NTP) {
    const int b2 = blk - NCVT;
    const int j0 = (b2 % 48) * 32, p0 = (b2 / 48) * 32;
    const int tx = tid & 31, ty = tid >> 5;
    for (int i = ty; i < 32; i += 8)
      tile[i][tx] = projw[(size_t)(p0 + i) * (3 * H) + j0 + tx];
    __syncthreads();
    for (int i = ty; i < 32; i += 8)
      projT[(size_t)(j0 + i) * P + p0 + tx] = tile[tx][i];
  } else {
    const int b3 = blk - NCVT - NTP;
    const int qq = b3 * 4;          // 4 q-rows per block, same b (48 % 4 == 0)
    const int b = qq / Q;
    const float4* qp4 = (const float4*)(q + (size_t)qq * D);
    for (int i = tid; i < 300; i += 256) qrow4[i] = qp4[i];
    __syncthreads();
    const int sub = tid >> 6, lane = tid & 63;
    float qsq = 0.f;
    for (int i = lane; i < 75; i += 64) {
      float4 v = qrow4[sub * 75 + i];
      qsq += v.x * v.x + v.y * v.y + v.z * v.z + v.w * v.w;
    }
#pragma unroll
    for (int off = 32; off; off >>= 1) qsq += __shfl_xor(qsq, off);
    const float qn = sqrtf(qsq);
    if (lane < A) {
      const float4* ap4 = (const float4*)(a + ((size_t)b * A + lane) * D);
      float dot = 0.f, asq = 0.f;
      for (int i = 0; i < 75; ++i) {
        float4 av = ap4[i], qv = qrow4[sub * 75 + i];
        dot += qv.x * av.x + qv.y * av.y + qv.z * av.z + qv.w * av.w;
        asq += av.x * av.x + av.y * av.y + av.z * av.z + av.w * av.w;
      }
      cosm[(size_t)(qq + sub) * A + lane] = dot / fmaxf(qn * sqrtf(asq), EPS_COS);
    }
  }
}

// ---------------------------------------------------------------------------
// Direct-from-L2 register MFMA GEMM. No staging LDS, no K-loop barriers.
// Each wave: independent 64x64 tile, 4x4 frags of 16x16x32, 1-deep prefetch.
// Epilogue: per-wave 8KB LDS transpose (XOR-swizzle) -> int4 stores.
// ---------------------------------------------------------------------------
__global__ void __launch_bounds__(256)
gemm_mfma(const short* __restrict__ qb, const short* __restrict__ ab,
          const short* __restrict__ smb, const short* __restrict__ ctxb,
          short* __restrict__ Sq, short* __restrict__ Sa_sm, short* __restrict__ Sa_ctx) {
  const int z = blockIdx.z;
  const short* X = (z == 0) ? qb : ab;
  const short* W = (z == 2) ? ctxb : smb;
  short* Out = (z == 0) ? Sq : (z == 1) ? Sa_sm : Sa_ctx;

  __shared__ short Cs[4][64 * 64];  // 32 KB, one 8KB region per wave
  const int tid = threadIdx.x, lane = tid & 63, wv = tid >> 6;
  const int wr = wv >> 1, wc = wv & 1;
  const int r16 = lane & 15, kq = lane >> 4;
  const size_t rowA0 = (size_t)blockIdx.y * 128 + wr * 64;
  const size_t colB0 = (size_t)blockIdx.x * 128 + wc * 64;
  const short* Xw = X + (rowA0 + r16) * KP + kq * 8;
  const short* Ww = W + (colB0 + r16) * KP + kq * 8;

  f32x4 acc[4][4];
#pragma unroll
  for (int mi = 0; mi < 4; ++mi)
#pragma unroll
    for (int ni = 0; ni < 4; ++ni) acc[mi][ni] = f32x4{0.f, 0.f, 0.f, 0.f};

  int4 cA[4], cB[4];
#pragma unroll
  for (int i = 0; i < 4; ++i) {
    cA[i] = *(const int4*)(Xw + i * 16 * KP);
    cB[i] = *(const int4*)(Ww + i * 16 * KP);
  }
#pragma unroll 1
  for (int ks = 0; ks < KP / 32; ++ks) {
    int4 nA[4], nB[4];
    if (ks < KP / 32 - 1) {
#pragma unroll
      for (int i = 0; i < 4; ++i) {
        nA[i] = *(const int4*)(Xw + i * 16 * KP + (ks + 1) * 32);
        nB[i] = *(const int4*)(Ww + i * 16 * KP + (ks + 1) * 32);
      }
    }
#pragma unroll
    for (int mi = 0; mi < 4; ++mi)
#pragma unroll
      for (int ni = 0; ni < 4; ++ni)
        acc[mi][ni] = __builtin_amdgcn_mfma_f32_16x16x32_bf16(
            __builtin_bit_cast(short8, cA[mi]),
            __builtin_bit_cast(short8, cB[ni]), acc[mi][ni], 0, 0, 0);
    if (ks < KP / 32 - 1) {
#pragma unroll
      for (int i = 0; i < 4; ++i) { cA[i] = nA[i]; cB[i] = nB[i]; }
    }
  }

  // per-wave epilogue (no __syncthreads: wave-private LDS region)
  short* cs = Cs[wv];
#pragma unroll
  for (int mi = 0; mi < 4; ++mi)
#pragma unroll
    for (int ni = 0; ni < 4; ++ni) {
      const int col = ni * 16 + r16;
#pragma unroll
      for (int r = 0; r < 4; ++r) {
        const int row = mi * 16 + kq * 4 + r;
        cs[row * 64 + (col ^ ((row & 7) << 3))] = f2bf(acc[mi][ni][r]);
      }
    }
#pragma unroll
  for (int it = 0; it < 8; ++it) {
    const int row = it * 8 + (lane >> 3);
    const int c8 = (lane & 7) * 8;
    const int4 v = *(const int4*)&cs[row * 64 + (c8 ^ ((row & 7) << 3))];
    *(int4*)&Out[(rowA0 + row) * CK + colB0 + c8] = v;
  }
}

// ---------------------------------------------------------------------------
// smpool: pooled[n,c] = relu(bias[c] + max_l sum_k S[n,l+k-4,c,k]); S bf16.
// ---------------------------------------------------------------------------
__global__ void smpool_k(const short* __restrict__ Sq, const short* __restrict__ Sa,
                         const float* __restrict__ bias, float* __restrict__ pooled) {
  __shared__ float sa[LP * CT * K];  // 38.4 KB
  __shared__ float red[8 * CT];
  const int n = blockIdx.y, ct = blockIdx.x, tid = threadIdx.x;
  const short* S = (n < B) ? Sq : Sa;
  const int nn = (n < B) ? n : n - B;

  float4* saz = (float4*)sa;
  for (int i = tid; i < LP * CT * K / 4; i += 256) saz[i] = float4{0.f, 0.f, 0.f, 0.f};
  __syncthreads();
  for (int i = tid; i < A * 20; i += 256) {
    const int pos = i / 20, cc = i % 20;
    const int4 v4 = *(const int4*)&S[((size_t)nn * A + pos) * CK + ct * 160 + cc * 8];
    const short8 v = __builtin_bit_cast(short8, v4);
    float4 lo = {bf2f(v[0]), bf2f(v[1]), bf2f(v[2]), bf2f(v[3])};
    float4 hi = {bf2f(v[4]), bf2f(v[5]), bf2f(v[6]), bf2f(v[7])};
    *(float4*)&sa[(pos + 4) * 160 + cc * 8] = lo;
    *(float4*)&sa[(pos + 4) * 160 + cc * 8 + 4] = hi;
  }
  __syncthreads();

  const int clane = tid & 31, part = tid >> 5;
  float best = -1e30f;
  for (int ch = part; ch < 13; ch += 8) {
    float sk[4][5];
#pragma unroll
    for (int p = 0; p < 4; ++p)
#pragma unroll
      for (int k = 0; k < K; ++k)
        sk[p][k] = sa[(4 * ch + p + k) * 160 + clane * 5 + k];
#pragma unroll
    for (int p = 0; p < 4; ++p) {
      float zv = sk[p][0] + sk[p][1] + sk[p][2] + sk[p][3] + sk[p][4];
      best = fmaxf(best, zv);
    }
  }
  red[part * CT + clane] = best;
  __syncthreads();
  if (tid < CT) {
    float m = red[tid];
#pragma unroll
    for (int g = 1; g < 8; ++g) m = fmaxf(m, red[g * CT + tid]);
    pooled[(size_t)n * C + ct * CT + tid] = fmaxf(m + bias[ct * CT + tid], 0.f);
  }
}

// ---------------------------------------------------------------------------
// ctxpool + mean over q'. S bf16. 8 q'-groups x 32 c-lanes, 6 q'/thread.
// ---------------------------------------------------------------------------
__global__ void ctxpool_k(const short* __restrict__ Sa, const float* __restrict__ cosm,
                          const float* __restrict__ bias, float* __restrict__ pbar) {
  __shared__ float sa[LP * CT * K];   // 38.4 KB
  __shared__ float cp3[Q * 72];       // 13.5 KB
  __shared__ float red[8 * CT];
  const int b = blockIdx.y, ct = blockIdx.x, tid = threadIdx.x;

  float4* saz = (float4*)sa;
  for (int i = tid; i < LP * CT * K / 4; i += 256) saz[i] = float4{0.f, 0.f, 0.f, 0.f};
  float4* cpz = (float4*)cp3;
  for (int i = tid; i < Q * 18; i += 256) cpz[i] = float4{0.f, 0.f, 0.f, 0.f};
  __syncthreads();
  for (int i = tid; i < A * 20; i += 256) {
    const int pos = i / 20, cc = i % 20;
    const int4 v4 = *(const int4*)&Sa[((size_t)b * A + pos) * CK + ct * 160 + cc * 8];
    const short8 v = __builtin_bit_cast(short8, v4);
    float4 lo = {bf2f(v[0]), bf2f(v[1]), bf2f(v[2]), bf2f(v[3])};
    float4 hi = {bf2f(v[4]), bf2f(v[5]), bf2f(v[6]), bf2f(v[7])};
    *(float4*)&sa[(pos + 4) * 160 + cc * 8] = lo;
    *(float4*)&sa[(pos + 4) * 160 + cc * 8 + 4] = hi;
  }
  for (int i = tid; i < Q * 12; i += 256) {
    const int qi = i / 12, t = i % 12;
    float4 v = *(const float4*)&cosm[((size_t)b * Q + qi) * A + t * 4];
    *(float4*)&cp3[qi * 72 + 4 + t * 4] = v;
  }
  __syncthreads();

  const int clane = tid & 31, grp = tid >> 5;
  float best[6];
#pragma unroll
  for (int j = 0; j < 6; ++j) best[j] = -1e30f;

  for (int ch = 0; ch < 13; ++ch) {
    float cw[6][8];
#pragma unroll
    for (int j = 0; j < 6; ++j) {
      const float4 a0 = *(const float4*)&cp3[(grp * 6 + j) * 72 + 4 * ch];
      const float4 a1 = *(const float4*)&cp3[(grp * 6 + j) * 72 + 4 * ch + 4];
      cw[j][0] = a0.x; cw[j][1] = a0.y; cw[j][2] = a0.z; cw[j][3] = a0.w;
      cw[j][4] = a1.x; cw[j][5] = a1.y; cw[j][6] = a1.z; cw[j][7] = a1.w;
    }
    float sk[4][5];
#pragma unroll
    for (int p = 0; p < 4; ++p)
#pragma unroll
      for (int k = 0; k < K; ++k)
        sk[p][k] = sa[(4 * ch + p + k) * 160 + clane * 5 + k];
#pragma unroll
    for (int p = 0; p < 4; ++p)
#pragma unroll
      for (int j = 0; j < 6; ++j) {
        float zv = 0.f;
#pragma unroll
        for (int k = 0; k < K; ++k) zv += cw[j][p + k] * sk[p][k];
        best[j] = fmaxf(best[j], zv);
      }
  }
  const float bc = bias[ct * CT + clane];
  float s = 0.f;
#pragma unroll
  for (int j = 0; j < 6; ++j) s += fmaxf(best[j] + bc, 0.f);
  red[grp * CT + clane] = s;
  __syncthreads();
  if (tid < CT) {
    float tot = 0.f;
#pragma unroll
    for (int g = 0; g < 8; ++g) tot += red[g * CT + tid];
    pbar[(size_t)b * C + ct * CT + tid] = tot * (1.0f / Q);
  }
}

// ---------------------------------------------------------------------------
// batched FC (z selects triple)
// ---------------------------------------------------------------------------
__global__ void fc_k(const float* __restrict__ pooled, const float* __restrict__ pbar,
                     const float* __restrict__ smW, const float* __restrict__ smb,
                     const float* __restrict__ ctxW, const float* __restrict__ ctxb,
                     float* __restrict__ acnn, float* __restrict__ bcnn,
                     float* __restrict__ attnf) {
  __shared__ float row[C];
  const int z = blockIdx.z;
  const float* in = (z == 0) ? pooled : (z == 1) ? pooled + (size_t)B * C : pbar;
  const float* Wm = (z == 2) ? ctxW : smW;
  const float* bs = (z == 2) ? ctxb : smb;
  float* out = (z == 0) ? acnn : (z == 1) ? bcnn : attnf;
  const int n = blockIdx.x;
  const int h = blockIdx.y * 256 + threadIdx.x;
  for (int c = threadIdx.x; c < C; c += 256) row[c] = in[(size_t)n * C + c];
  __syncthreads();
  float acc = bs[h];
  const float* w = Wm + (size_t)h * C;
  for (int c = 0; c < C; ++c) acc += row[c] * w[c];
  out[(size_t)n * H + h] = acc;
}

// ---------------------------------------------------------------------------
// proj, split 8-way over j: partial[g][b][p] = sum_{j in chunk g} cat[b,j]*WT[j,p]
// ---------------------------------------------------------------------------
__global__ void proj_k(const float* __restrict__ acnn, const float* __restrict__ bcnn,
                       const float* __restrict__ attnf, const float* __restrict__ WT,
                       float* __restrict__ partial) {
  __shared__ float cs[192];
  const int b = blockIdx.x, g = blockIdx.y, tid = threadIdx.x;
  const int js = g * 192;
  if (tid < 192) {
    const int j = js + tid;
    float v;
    if (j < H)          v = acnn[(size_t)b * H + j];
    else if (j < 2 * H) v = bcnn[(size_t)b * H + j - H];
    else                v = attnf[(size_t)b * H + j - 2 * H];
    cs[tid] = v;
  }
  __syncthreads();
  float a0 = 0.f, a1 = 0.f;
  for (int j = 0; j < 192; ++j) {
    const float c = cs[j];
    a0 += c * WT[(size_t)(js + j) * P + tid];
    a1 += c * WT[(size_t)(js + j) * P + tid + 256];
  }
  partial[((size_t)g * B + b) * P + tid] = a0;
  partial[((size_t)g * B + b) * P + tid + 256] = a1;
}

// ---------------------------------------------------------------------------
// bnmid: sum proj partials -> comb; batch stats over B (two-pass); tanh -> t.
// grid = P/64 blocks x 256 thr; thread = (rgroup 0..3, p-lane 0..63), 8 r each.
// ---------------------------------------------------------------------------
__global__ void bnmid_k(const float* __restrict__ partial, const float* __restrict__ proj_b,
                        const float* __restrict__ gamma, const float* __restrict__ beta,
                        float* __restrict__ t) {
  __shared__ float s1[4][64], s2[4][64];
  const int pl = threadIdx.x & 63, rg = threadIdx.x >> 6;
  const int p = blockIdx.x * 64 + pl;
  const float pb = proj_b[p];
  float v[8];
#pragma unroll
  for (int i = 0; i < 8; ++i) {
    const int r = rg * 8 + i;
    float s = pb;
#pragma unroll
    for (int g = 0; g < NJ; ++g) s += partial[((size_t)g * B + r) * P + p];
    v[i] = s;
  }
  float a = 0.f;
#pragma unroll
  for (int i = 0; i < 8; ++i) a += v[i];
  s1[rg][pl] = a;
  __syncthreads();
  const float mu = (s1[0][pl] + s1[1][pl] + s1[2][pl] + s1[3][pl]) * (1.0f / B);
  float b2 = 0.f;
#pragma unroll
  for (int i = 0; i < 8; ++i) { const float d = v[i] - mu; b2 += d * d; }
  s2[rg][pl] = b2;
  __syncthreads();
  const float var = (s2[0][pl] + s2[1][pl] + s2[2][pl] + s2[3][pl]) * (1.0f / B);
  const float inv = rsqrtf(var + EPS_BN);
  const float g = gamma[p], be = beta[p];
#pragma unroll
  for (int i = 0; i < 8; ++i)
    t[(size_t)(rg * 8 + i) * P + p] = tanhf((v[i] - mu) * inv * g + be);
}

// ---------------------------------------------------------------------------
// final FC: logits[b,cl] = out_b[cl] + t[b,:] . out_w[cl,:]
// ---------------------------------------------------------------------------
__global__ void out_k(const float* __restrict__ t, const float* __restrict__ W,
                      const float* __restrict__ bias, float* __restrict__ out) {
  const int tid = threadIdx.x;  // 512
  const int o = tid >> 3, lane8 = tid & 7;
  const int bb = o >> 1, cl = o & 1;
  float acc = 0.f;
  for (int j = lane8; j < P; j += 8) acc += t[(size_t)bb * P + j] * W[cl * P + j];
#pragma unroll
  for (int off = 4; off; off >>= 1) acc += __shfl_down(acc, off);
  if (lane8 == 0) out[bb * NCLS + cl] = acc + bias[cl];
}

extern "C" void kernel_launch(void* const* d_in, const int* in_sizes, int n_in,
                              void* d_out, int out_size, void* d_ws, size_t ws_size,
                              hipStream_t stream) {
  const float* q       = (const float*)d_in[0];
  const float* a       = (const float*)d_in[1];
  const float* sm_w    = (const float*)d_in[2];
  const float* sm_b    = (const float*)d_in[3];
  const float* sm_fcw  = (const float*)d_in[4];
  const float* sm_fcb  = (const float*)d_in[5];
  const float* ctx_w   = (const float*)d_in[6];
  const float* ctx_b   = (const float*)d_in[7];
  const float* ctx_fcw = (const float*)d_in[8];
  const float* ctx_fcb = (const float*)d_in[9];
  const float* proj_w  = (const float*)d_in[10];
  const float* proj_b  = (const float*)d_in[11];
  const float* gamma   = (const float*)d_in[12];
  const float* beta    = (const float*)d_in[13];
  const float* out_w   = (const float*)d_in[14];
  const float* out_b   = (const float*)d_in[15];

  float* ws = (float*)d_ws;
  size_t off = 0;
  auto alloc = [&](size_t n) { float* p = ws + off; off += n; return p; };
  short* Sq     = (short*)alloc((size_t)M * CK / 2);
  short* Sa_sm  = (short*)alloc((size_t)M * CK / 2);
  short* Sa_ctx = (short*)alloc((size_t)M * CK / 2);
  float* cosm   = alloc((size_t)B * Q * A);
  float* pooled = alloc((size_t)2 * B * C);
  float* pbar   = alloc((size_t)B * C);
  float* acnn   = alloc((size_t)B * H);
  float* bcnn   = alloc((size_t)B * H);
  float* attnf  = alloc((size_t)B * H);
  float* projT  = alloc((size_t)3 * H * P);
  float* partial= alloc((size_t)NJ * B * P);
  float* tbuf   = alloc((size_t)B * P);
  short* qb     = (short*)alloc((size_t)M * KP / 2);
  short* ab     = (short*)alloc((size_t)M * KP / 2);
  short* smb2   = (short*)alloc((size_t)CK * KP / 2);
  short* ctxb2  = (short*)alloc((size_t)CK * KP / 2);

  prep_k<<<NCVT + NTP + NCOS, 256, 0, stream>>>(q, a, sm_w, ctx_w, proj_w,
                                                qb, ab, smb2, ctxb2, projT, cosm);
  gemm_mfma<<<dim3(CK / 128, M / 128, 3), 256, 0, stream>>>(qb, ab, smb2, ctxb2,
                                                            Sq, Sa_sm, Sa_ctx);
  smpool_k<<<dim3(C / CT, 2 * B), 256, 0, stream>>>(Sq, Sa_sm, sm_b, pooled);
  ctxpool_k<<<dim3(C / CT, B), 256, 0, stream>>>(Sa_ctx, cosm, ctx_b, pbar);
  fc_k<<<dim3(B, H / 256, 3), 256, 0, stream>>>(pooled, pbar, sm_fcw, sm_fcb,
                                                ctx_fcw, ctx_fcb, acnn, bcnn, attnf);
  proj_k<<<dim3(B, NJ), 256, 0, stream>>>(acnn, bcnn, attnf, projT, partial);
  bnmid_k<<<P / 64, 256, 0, stream>>>(partial, proj_b, gamma, beta, tbuf);
  out_k<<<1, 512, 0, stream>>>(tbuf, out_w, out_b, (float*)d_out);
}

// Round 7
// 114.639 us; speedup vs baseline: 4.7881x; 1.0261x over previous
//
#include <hip/hip_runtime.h>
#include <math.h>
#include <stdint.h>

namespace {
constexpr int B = 32, Q = 48, A = 48, D = 300;
constexpr int C = 512, K = 5, H = 512, P = 512, NCLS = 2;
constexpr int CK = C * K;         // 2560
constexpr int M = B * Q;          // 1536
constexpr int KP = 320;           // K padded for bf16 MFMA
constexpr float EPS_COS = 1e-6f, EPS_BN = 1e-5f;
constexpr int NCVT = (2 * (M + CK) * 40) / 256;  // 1280 blocks
constexpr int NTP  = (3 * H / 32) * (P / 32);    // 768 blocks
constexpr int NCOS = M / 4;                      // 384 blocks
constexpr int NJ = 8;                            // proj j-chunks (1536/192)
}
using short8 = __attribute__((ext_vector_type(8))) short;
using f32x4  = __attribute__((ext_vector_type(4))) float;

__device__ inline short f2bf(float v) {
  uint32_t u = __builtin_bit_cast(uint32_t, v);
  return (short)((u + 0x7fffu + ((u >> 16) & 1u)) >> 16);  // RNE
}

// ---------------------------------------------------------------------------
// prep: [0,NCVT) fp32->bf16 pad-to-320 | [.,+NTP) proj_w transpose | cos sim
// ---------------------------------------------------------------------------
__global__ void prep_k(const float* __restrict__ q, const float* __restrict__ a,
                       const float* __restrict__ smw, const float* __restrict__ ctxw,
                       const float* __restrict__ projw,
                       short* __restrict__ qb, short* __restrict__ ab,
                       short* __restrict__ smb, short* __restrict__ ctxb,
                       float* __restrict__ projT, float* __restrict__ cosm) {
  __shared__ float tile[32][33];
  __shared__ float4 qrow4[300];
  const int blk = blockIdx.x, tid = threadIdx.x;
  if (blk < NCVT) {
    const int idx = blk * 256 + tid;
    const int row = idx / 40, ch = idx - row * 40;
    const float* src; short* dst; int r;
    if (row < M)              { src = q;    dst = qb;   r = row; }
    else if (row < 2 * M)     { src = a;    dst = ab;   r = row - M; }
    else if (row < 2 * M + CK){ src = smw;  dst = smb;  r = row - 2 * M; }
    else                      { src = ctxw; dst = ctxb; r = row - 2 * M - CK; }
    short tmp[8];
#pragma unroll
    for (int e = 0; e < 8; ++e) {
      const int k = ch * 8 + e;
      tmp[e] = (k < D) ? f2bf(src[(size_t)r * D + k]) : (short)0;
    }
    *(int4*)&dst[(size_t)r * KP + ch * 8] = *(const int4*)tmp;
  } else if (blk < NCVT + NTP) {
    const int b2 = blk - NCVT;
    const int j0 = (b2 % 48) * 32, p0 = (b2 / 48) * 32;
    const int tx = tid & 31, ty = tid >> 5;
    for (int i = ty; i < 32; i += 8)
      tile[i][tx] = projw[(size_t)(p0 + i) * (3 * H) + j0 + tx];
    __syncthreads();
    for (int i = ty; i < 32; i += 8)
      projT[(size_t)(j0 + i) * P + p0 + tx] = tile[tx][i];
  } else {
    const int b3 = blk - NCVT - NTP;
    const int qq = b3 * 4;          // 4 q-rows per block, same b (48 % 4 == 0)
    const int b = qq / Q;
    const float4* qp4 = (const float4*)(q + (size_t)qq * D);
    for (int i = tid; i < 300; i += 256) qrow4[i] = qp4[i];
    __syncthreads();
    const int sub = tid >> 6, lane = tid & 63;
    float qsq = 0.f;
    for (int i = lane; i < 75; i += 64) {
      float4 v = qrow4[sub * 75 + i];
      qsq += v.x * v.x + v.y * v.y + v.z * v.z + v.w * v.w;
    }
#pragma unroll
    for (int off = 32; off; off >>= 1) qsq += __shfl_xor(qsq, off);
    const float qn = sqrtf(qsq);
    if (lane < A) {
      const float4* ap4 = (const float4*)(a + ((size_t)b * A + lane) * D);
      float dot = 0.f, asq = 0.f;
      for (int i = 0; i < 75; ++i) {
        float4 av = ap4[i], qv = qrow4[sub * 75 + i];
        dot += qv.x * av.x + qv.y * av.y + qv.z * av.z + qv.w * av.w;
        asq += av.x * av.x + av.y * av.y + av.z * av.z + av.w * av.w;
      }
      cosm[(size_t)(qq + sub) * A + lane] = dot / fmaxf(qn * sqrtf(asq), EPS_COS);
    }
  }
}

// ---------------------------------------------------------------------------
// fused_sm: GEMM (48x320 S-tile via MFMA, direct-from-L2 frags) + max-pool
// + bias + relu -> pooled[n, 64ch].  grid (8 cg, 64 n); n<32 -> q path.
// S never touches global memory.
// ---------------------------------------------------------------------------
__global__ void __launch_bounds__(256)
fused_sm(const short* __restrict__ qb, const short* __restrict__ ab,
         const short* __restrict__ smb, const float* __restrict__ bias,
         float* __restrict__ pooled) {
  __shared__ float Sl[4][56][80];   // 71.68 KB, wave-private regions
  __shared__ float red[4][64];
  const int cg = blockIdx.x, n = blockIdx.y;
  const int tid = threadIdx.x, lane = tid & 63, wv = tid >> 6;
  const int r16 = lane & 15, kq = lane >> 4;
  const short* X = (n < B) ? qb + (size_t)n * 48 * KP : ab + (size_t)(n - B) * 48 * KP;
  const int gc0 = cg * 320 + wv * 80;
  const short* Xw = X + (size_t)r16 * KP + kq * 8;
  const short* Wt = smb + (size_t)(gc0 + r16) * KP + kq * 8;

  // zero pad rows 0..3 and 52..55 of my wave region
  for (int i = lane; i < 640; i += 64) {
    const int rr = i / 80, cc = i % 80;
    Sl[wv][rr < 4 ? rr : rr + 48][cc] = 0.f;
  }

  f32x4 acc[3][5];
#pragma unroll
  for (int mi = 0; mi < 3; ++mi)
#pragma unroll
    for (int ni = 0; ni < 5; ++ni) acc[mi][ni] = f32x4{0.f, 0.f, 0.f, 0.f};

  int4 cA[3], cB[5];
#pragma unroll
  for (int i = 0; i < 3; ++i) cA[i] = *(const int4*)(Xw + i * 16 * KP);
#pragma unroll
  for (int i = 0; i < 5; ++i) cB[i] = *(const int4*)(Wt + i * 16 * KP);
#pragma unroll 1
  for (int ks = 0; ks < KP / 32; ++ks) {
    int4 nA[3], nB[5];
    if (ks < KP / 32 - 1) {
#pragma unroll
      for (int i = 0; i < 3; ++i) nA[i] = *(const int4*)(Xw + i * 16 * KP + (ks + 1) * 32);
#pragma unroll
      for (int i = 0; i < 5; ++i) nB[i] = *(const int4*)(Wt + i * 16 * KP + (ks + 1) * 32);
    }
#pragma unroll
    for (int mi = 0; mi < 3; ++mi)
#pragma unroll
      for (int ni = 0; ni < 5; ++ni)
        acc[mi][ni] = __builtin_amdgcn_mfma_f32_16x16x32_bf16(
            __builtin_bit_cast(short8, cA[mi]),
            __builtin_bit_cast(short8, cB[ni]), acc[mi][ni], 0, 0, 0);
    if (ks < KP / 32 - 1) {
#pragma unroll
      for (int i = 0; i < 3; ++i) cA[i] = nA[i];
#pragma unroll
      for (int i = 0; i < 5; ++i) cB[i] = nB[i];
    }
  }
  // acc -> LDS (C/D layout: row = mi*16 + kq*4 + r, col = ni*16 + r16)
#pragma unroll
  for (int mi = 0; mi < 3; ++mi)
#pragma unroll
    for (int ni = 0; ni < 5; ++ni)
#pragma unroll
      for (int r = 0; r < 4; ++r)
        Sl[wv][mi * 16 + kq * 4 + r + 4][ni * 16 + r16] = acc[mi][ni][r];
  __syncthreads();

  // pool: ch = tid&63, part = tid>>6 handles 13 l's
  const int ch = tid & 63, part = tid >> 6;
  const int w2 = ch >> 4, cl = (ch & 15) * 5;
  float best = -1e30f;
#pragma unroll
  for (int j = 0; j < 13; ++j) {
    const int l = part * 13 + j;
    const float z = Sl[w2][l + 0][cl + 0] + Sl[w2][l + 1][cl + 1] + Sl[w2][l + 2][cl + 2]
                  + Sl[w2][l + 3][cl + 3] + Sl[w2][l + 4][cl + 4];
    best = fmaxf(best, z);
  }
  red[part][ch] = best;
  __syncthreads();
  if (tid < 64) {
    const float m = fmaxf(fmaxf(red[0][tid], red[1][tid]), fmaxf(red[2][tid], red[3][tid]));
    pooled[(size_t)n * C + cg * 64 + tid] = fmaxf(m + bias[cg * 64 + tid], 0.f);
  }
}

// ---------------------------------------------------------------------------
// fused_ctx: GEMM (48x320 S_ctx tile) + cos-weighted max-pool + relu + mean
// over q' -> pbar[b, 64ch].  grid (8 cg, 32 b).
// ---------------------------------------------------------------------------
__global__ void __launch_bounds__(256)
fused_ctx(const short* __restrict__ ab, const short* __restrict__ ctxb,
          const float* __restrict__ cosm, const float* __restrict__ bias,
          float* __restrict__ pbar) {
  __shared__ float Sl[4][56][80];   // 71.68 KB
  __shared__ float cosl[48][56];    // 10.5 KB
  __shared__ float red[2][8][32];
  const int cg = blockIdx.x, b = blockIdx.y;
  const int tid = threadIdx.x, lane = tid & 63, wv = tid >> 6;
  const int r16 = lane & 15, kq = lane >> 4;
  const short* X = ab + (size_t)b * 48 * KP;
  const int gc0 = cg * 320 + wv * 80;
  const short* Xw = X + (size_t)r16 * KP + kq * 8;
  const short* Wt = ctxb + (size_t)(gc0 + r16) * KP + kq * 8;

  for (int i = lane; i < 640; i += 64) {
    const int rr = i / 80, cc = i % 80;
    Sl[wv][rr < 4 ? rr : rr + 48][cc] = 0.f;
  }
  // stage cos with zero-padded position axis: cosl[q][pos+4]
  for (int i = tid; i < 48 * 56; i += 256) {
    const int qi = i / 56, p4 = i % 56;
    cosl[qi][p4] = (p4 >= 4 && p4 < 52)
                 ? cosm[((size_t)b * Q + qi) * A + p4 - 4] : 0.f;
  }

  f32x4 acc[3][5];
#pragma unroll
  for (int mi = 0; mi < 3; ++mi)
#pragma unroll
    for (int ni = 0; ni < 5; ++ni) acc[mi][ni] = f32x4{0.f, 0.f, 0.f, 0.f};

  int4 cA[3], cB[5];
#pragma unroll
  for (int i = 0; i < 3; ++i) cA[i] = *(const int4*)(Xw + i * 16 * KP);
#pragma unroll
  for (int i = 0; i < 5; ++i) cB[i] = *(const int4*)(Wt + i * 16 * KP);
#pragma unroll 1
  for (int ks = 0; ks < KP / 32; ++ks) {
    int4 nA[3], nB[5];
    if (ks < KP / 32 - 1) {
#pragma unroll
      for (int i = 0; i < 3; ++i) nA[i] = *(const int4*)(Xw + i * 16 * KP + (ks + 1) * 32);
#pragma unroll
      for (int i = 0; i < 5; ++i) nB[i] = *(const int4*)(Wt + i * 16 * KP + (ks + 1) * 32);
    }
#pragma unroll
    for (int mi = 0; mi < 3; ++mi)
#pragma unroll
      for (int ni = 0; ni < 5; ++ni)
        acc[mi][ni] = __builtin_amdgcn_mfma_f32_16x16x32_bf16(
            __builtin_bit_cast(short8, cA[mi]),
            __builtin_bit_cast(short8, cB[ni]), acc[mi][ni], 0, 0, 0);
    if (ks < KP / 32 - 1) {
#pragma unroll
      for (int i = 0; i < 3; ++i) cA[i] = nA[i];
#pragma unroll
      for (int i = 0; i < 5; ++i) cB[i] = nB[i];
    }
  }
#pragma unroll
  for (int mi = 0; mi < 3; ++mi)
#pragma unroll
    for (int ni = 0; ni < 5; ++ni)
#pragma unroll
      for (int r = 0; r < 4; ++r)
        Sl[wv][mi * 16 + kq * 4 + r + 4][ni * 16 + r16] = acc[mi][ni][r];
  __syncthreads();

  // pool: grp = tid>>5 owns 6 q's; clane = tid&31; 2 channels per thread
  const int clane = tid & 31, grp = tid >> 5;
  float best[2][6];
#pragma unroll
  for (int cc = 0; cc < 2; ++cc)
#pragma unroll
    for (int j = 0; j < 6; ++j) best[cc][j] = -1e30f;

  for (int ch13 = 0; ch13 < 13; ++ch13) {
    float cw[6][8];
#pragma unroll
    for (int j = 0; j < 6; ++j) {
      const float4 a0 = *(const float4*)&cosl[grp * 6 + j][4 * ch13];
      const float4 a1 = *(const float4*)&cosl[grp * 6 + j][4 * ch13 + 4];
      cw[j][0] = a0.x; cw[j][1] = a0.y; cw[j][2] = a0.z; cw[j][3] = a0.w;
      cw[j][4] = a1.x; cw[j][5] = a1.y; cw[j][6] = a1.z; cw[j][7] = a1.w;
    }
#pragma unroll
    for (int cc = 0; cc < 2; ++cc) {
      const int ch = cc * 32 + clane;
      const int w2 = ch >> 4, cl = (ch & 15) * 5;
      float sk[4][5];
#pragma unroll
      for (int p = 0; p < 4; ++p)
#pragma unroll
        for (int k = 0; k < K; ++k)
          sk[p][k] = Sl[w2][4 * ch13 + p + k][cl + k];
#pragma unroll
      for (int p = 0; p < 4; ++p)
#pragma unroll
        for (int j = 0; j < 6; ++j) {
          float zv = 0.f;
#pragma unroll
          for (int k = 0; k < K; ++k) zv += cw[j][p + k] * sk[p][k];
          best[cc][j] = fmaxf(best[cc][j], zv);
        }
    }
  }
#pragma unroll
  for (int cc = 0; cc < 2; ++cc) {
    const float bc = bias[cg * 64 + cc * 32 + clane];
    float s = 0.f;
#pragma unroll
    for (int j = 0; j < 6; ++j) s += fmaxf(best[cc][j] + bc, 0.f);
    red[cc][grp][clane] = s;
  }
  __syncthreads();
  if (tid < 64) {
    const int cc = tid >> 5, cl2 = tid & 31;
    float tot = 0.f;
#pragma unroll
    for (int g = 0; g < 8; ++g) tot += red[cc][g][cl2];
    pbar[(size_t)b * C + cg * 64 + cc * 32 + cl2] = tot * (1.0f / Q);
  }
}

// ---------------------------------------------------------------------------
// batched FC (z selects triple)
// ---------------------------------------------------------------------------
__global__ void fc_k(const float* __restrict__ pooled, const float* __restrict__ pbar,
                     const float* __restrict__ smW, const float* __restrict__ smb,
                     const float* __restrict__ ctxW, const float* __restrict__ ctxb,
                     float* __restrict__ acnn, float* __restrict__ bcnn,
                     float* __restrict__ attnf) {
  __shared__ float row[C];
  const int z = blockIdx.z;
  const float* in = (z == 0) ? pooled : (z == 1) ? pooled + (size_t)B * C : pbar;
  const float* Wm = (z == 2) ? ctxW : smW;
  const float* bs = (z == 2) ? ctxb : smb;
  float* out = (z == 0) ? acnn : (z == 1) ? bcnn : attnf;
  const int n = blockIdx.x;
  const int h = blockIdx.y * 256 + threadIdx.x;
  for (int c = threadIdx.x; c < C; c += 256) row[c] = in[(size_t)n * C + c];
  __syncthreads();
  float acc = bs[h];
  const float* w = Wm + (size_t)h * C;
  for (int c = 0; c < C; ++c) acc += row[c] * w[c];
  out[(size_t)n * H + h] = acc;
}

// ---------------------------------------------------------------------------
// proj, split 8-way over j: partial[g][b][p] = sum_{j in chunk g} cat[b,j]*WT[j,p]
// ---------------------------------------------------------------------------
__global__ void proj_k(const float* __restrict__ acnn, const float* __restrict__ bcnn,
                       const float* __restrict__ attnf, const float* __restrict__ WT,
                       float* __restrict__ partial) {
  __shared__ float cs[192];
  const int b = blockIdx.x, g = blockIdx.y, tid = threadIdx.x;
  const int js = g * 192;
  if (tid < 192) {
    const int j = js + tid;
    float v;
    if (j < H)          v = acnn[(size_t)b * H + j];
    else if (j < 2 * H) v = bcnn[(size_t)b * H + j - H];
    else                v = attnf[(size_t)b * H + j - 2 * H];
    cs[tid] = v;
  }
  __syncthreads();
  float a0 = 0.f, a1 = 0.f;
  for (int j = 0; j < 192; ++j) {
    const float c = cs[j];
    a0 += c * WT[(size_t)(js + j) * P + tid];
    a1 += c * WT[(size_t)(js + j) * P + tid + 256];
  }
  partial[((size_t)g * B + b) * P + tid] = a0;
  partial[((size_t)g * B + b) * P + tid + 256] = a1;
}

// ---------------------------------------------------------------------------
// bnmid: sum proj partials; batch stats over B; tanh -> t.
// ---------------------------------------------------------------------------
__global__ void bnmid_k(const float* __restrict__ partial, const float* __restrict__ proj_b,
                        const float* __restrict__ gamma, const float* __restrict__ beta,
                        float* __restrict__ t) {
  __shared__ float s1[4][64], s2[4][64];
  const int pl = threadIdx.x & 63, rg = threadIdx.x >> 6;
  const int p = blockIdx.x * 64 + pl;
  const float pb = proj_b[p];
  float v[8];
#pragma unroll
  for (int i = 0; i < 8; ++i) {
    const int r = rg * 8 + i;
    float s = pb;
#pragma unroll
    for (int g = 0; g < NJ; ++g) s += partial[((size_t)g * B + r) * P + p];
    v[i] = s;
  }
  float a = 0.f;
#pragma unroll
  for (int i = 0; i < 8; ++i) a += v[i];
  s1[rg][pl] = a;
  __syncthreads();
  const float mu = (s1[0][pl] + s1[1][pl] + s1[2][pl] + s1[3][pl]) * (1.0f / B);
  float b2 = 0.f;
#pragma unroll
  for (int i = 0; i < 8; ++i) { const float d = v[i] - mu; b2 += d * d; }
  s2[rg][pl] = b2;
  __syncthreads();
  const float var = (s2[0][pl] + s2[1][pl] + s2[2][pl] + s2[3][pl]) * (1.0f / B);
  const float inv = rsqrtf(var + EPS_BN);
  const float g = gamma[p], be = beta[p];
#pragma unroll
  for (int i = 0; i < 8; ++i)
    t[(size_t)(rg * 8 + i) * P + p] = tanhf((v[i] - mu) * inv * g + be);
}

// ---------------------------------------------------------------------------
// final FC: logits[b,cl] = out_b[cl] + t[b,:] . out_w[cl,:]
// ---------------------------------------------------------------------------
__global__ void out_k(const float* __restrict__ t, const float* __restrict__ W,
                      const float* __restrict__ bias, float* __restrict__ out) {
  const int tid = threadIdx.x;  // 512
  const int o = tid >> 3, lane8 = tid & 7;
  const int bb = o >> 1, cl = o & 1;
  float acc = 0.f;
  for (int j = lane8; j < P; j += 8) acc += t[(size_t)bb * P + j] * W[cl * P + j];
#pragma unroll
  for (int off = 4; off; off >>= 1) acc += __shfl_down(acc, off);
  if (lane8 == 0) out[bb * NCLS + cl] = acc + bias[cl];
}

extern "C" void kernel_launch(void* const* d_in, const int* in_sizes, int n_in,
                              void* d_out, int out_size, void* d_ws, size_t ws_size,
                              hipStream_t stream) {
  const float* q       = (const float*)d_in[0];
  const float* a       = (const float*)d_in[1];
  const float* sm_w    = (const float*)d_in[2];
  const float* sm_b    = (const float*)d_in[3];
  const float* sm_fcw  = (const float*)d_in[4];
  const float* sm_fcb  = (const float*)d_in[5];
  const float* ctx_w   = (const float*)d_in[6];
  const float* ctx_b   = (const float*)d_in[7];
  const float* ctx_fcw = (const float*)d_in[8];
  const float* ctx_fcb = (const float*)d_in[9];
  const float* proj_w  = (const float*)d_in[10];
  const float* proj_b  = (const float*)d_in[11];
  const float* gamma   = (const float*)d_in[12];
  const float* beta    = (const float*)d_in[13];
  const float* out_w   = (const float*)d_in[14];
  const float* out_b   = (const float*)d_in[15];

  float* ws = (float*)d_ws;
  size_t off = 0;
  auto alloc = [&](size_t n) { float* p = ws + off; off += n; return p; };
  float* cosm   = alloc((size_t)B * Q * A);
  float* pooled = alloc((size_t)2 * B * C);
  float* pbar   = alloc((size_t)B * C);
  float* acnn   = alloc((size_t)B * H);
  float* bcnn   = alloc((size_t)B * H);
  float* attnf  = alloc((size_t)B * H);
  float* projT  = alloc((size_t)3 * H * P);
  float* partial= alloc((size_t)NJ * B * P);
  float* tbuf   = alloc((size_t)B * P);
  short* qb     = (short*)alloc((size_t)M * KP / 2);
  short* ab     = (short*)alloc((size_t)M * KP / 2);
  short* smb2   = (short*)alloc((size_t)CK * KP / 2);
  short* ctxb2  = (short*)alloc((size_t)CK * KP / 2);

  prep_k<<<NCVT + NTP + NCOS, 256, 0, stream>>>(q, a, sm_w, ctx_w, proj_w,
                                                qb, ab, smb2, ctxb2, projT, cosm);
  fused_sm<<<dim3(8, 2 * B), 256, 0, stream>>>(qb, ab, smb2, sm_b, pooled);
  fused_ctx<<<dim3(8, B), 256, 0, stream>>>(ab, ctxb2, cosm, ctx_b, pbar);
  fc_k<<<dim3(B, H / 256, 3), 256, 0, stream>>>(pooled, pbar, sm_fcw, sm_fcb,
                                                ctx_fcw, ctx_fcb, acnn, bcnn, attnf);
  proj_k<<<dim3(B, NJ), 256, 0, stream>>>(acnn, bcnn, attnf, projT, partial);
  bnmid_k<<<P / 64, 256, 0, stream>>>(partial, proj_b, gamma, beta, tbuf);
  out_k<<<1, 512, 0, stream>>>(tbuf, out_w, out_b, (float*)d_out);
}